// Round 10
// baseline (311.178 us; speedup 1.0000x reference)
//
#include <hip/hip_runtime.h>
#include <math.h>

#define BATCH 8
#define NPTS 2048
#define CH 64
#define KNB 16
#define M_SAMPLES (BATCH * NPTS * KNB)   // 262144
#define FIXSCALE 1048576.0               // 2^20 fixed-point for deterministic atomics
#define NREP 4                           // Gfix replicas (atomic-contention split)

// ws layout (float offsets) — peak 823552 floats = 3.29 MB (unchanged):
//   rel   : [0, 786432)          262144 * 3 f32
//   s1t1  : [786432, 786560)
//   s2t2  : [786560, 786688)
//   part1 : [786688, 823552)     4096 blocks * 9  (knn -> fin1; dead after fin1)
//   Gfix  : [786688, 819968)     4 replicas * 4160 u64 = 33280 floats, aliases
//                                part1 (zeroed in fin1 AFTER part1 consumed)
#define WS_REL   0
#define WS_S1T1  786432
#define WS_S2T2  786560
#define WS_PART1 786688
#define WS_GFIX  786688

#define SURV_CAP 192
#define D2_EPS 1e-4f

__device__ __forceinline__ unsigned long long u64min(unsigned long long a, unsigned long long b) { return a < b ? a : b; }
__device__ __forceinline__ unsigned long long u64max(unsigned long long a, unsigned long long b) { return a > b ? a : b; }

__device__ __forceinline__ unsigned long long bitonic64(unsigned long long v, int lane) {
#pragma unroll
    for (int k = 2; k <= 64; k <<= 1)
#pragma unroll
        for (int d = k >> 1; d >= 1; d >>= 1) {
            unsigned long long o = __shfl_xor(v, d, 64);
            bool keepmin = (((lane & d) == 0) == ((lane & k) == 0));
            v = keepmin ? u64min(v, o) : u64max(v, o);
        }
    return v;
}

__device__ __forceinline__ unsigned long long cand_key(const float4 pq, const float4 pj, int j, int q) {
    float dot = pq.x * pj.x + pq.y * pj.y + pq.z * pj.z;
    float d2 = fmaxf((pq.w + pj.w) - 2.0f * dot, 0.0f);
    unsigned long long key = ((unsigned long long)__float_as_uint(d2) << 32) | (unsigned int)j;
    return (j == q) ? ~0ull : key;
}

// ---------------- K1: KNN (R7-verbatim, proven) ----------------
__global__ __launch_bounds__(256) void knn_rel_kernel(const float* __restrict__ xyz,
                                                      float* __restrict__ rel,
                                                      float* __restrict__ part1) {
    __shared__ float4 pts[NPTS];
    __shared__ unsigned long long surv[4][SURV_CAP];
    __shared__ unsigned int wavecnt[4];
    __shared__ float red9[4][9];

    const int b     = blockIdx.x >> 9;
    const int qbase = (blockIdx.x & 511) * 4;
    const int tid   = threadIdx.x;
    const int wave  = tid >> 6, lane = tid & 63;

    const float* xb = xyz + (size_t)b * 3 * NPTS;
    for (int j = tid; j < NPTS; j += 256) {
        float x = xb[j], y = xb[NPTS + j], z = xb[2 * NPTS + j];
        pts[j] = make_float4(x, y, z, (x * x + y * y) + z * z);
    }
    __syncthreads();

    const int q = qbase + wave;
    const float4 pq = pts[q];

    unsigned long long lm = ~0ull;
#pragma unroll
    for (int t = 0; t < 32; ++t) {
        const int j = t * 64 + lane;
        lm = u64min(lm, cand_key(pq, pts[j], j, q));
    }
    unsigned long long sorted = bitonic64(lm, lane);
    const float Td2 = __uint_as_float((unsigned int)(__shfl(sorted, 15, 64) >> 32)) + D2_EPS;

    if (lane == 0) wavecnt[wave] = 0u;
#pragma unroll
    for (int t = 0; t < 32; ++t) {
        const int j = t * 64 + lane;
        unsigned long long key = cand_key(pq, pts[j], j, q);
        float d2 = __uint_as_float((unsigned int)(key >> 32));
        if (d2 <= Td2) {
            unsigned int pos = atomicAdd(&wavecnt[wave], 1u);
            if (pos < SURV_CAP) surv[wave][pos] = key;
        }
    }
    const unsigned int total = wavecnt[wave];

    unsigned long long wkey = ~0ull;
    bool ok = false;
    if (total >= 16u && total <= 64u) {
        unsigned long long s0 = (lane < (int)total) ? surv[wave][lane] : ~0ull;
        wkey = bitonic64(s0, lane);
        unsigned long long nxt = __shfl_down(wkey, 1, 64);
        ok = __all((lane == 63) || (wkey <= nxt)) != 0;
    }
    if (!ok) {
        unsigned long long last = 0ull; bool first = true;
#pragma unroll 1
        for (int r = 0; r < 16; ++r) {
            unsigned long long m = ~0ull;
#pragma unroll
            for (int t = 0; t < 32; ++t) {
                const int j = t * 64 + lane;
                unsigned long long key = cand_key(pq, pts[j], j, q);
                if (first || key > last) m = u64min(m, key);
            }
#pragma unroll
            for (int d = 1; d < 64; d <<= 1) m = u64min(m, __shfl_xor(m, d, 64));
            if (lane == r) wkey = m;
            last = m; first = false;
        }
    }

    float rr0 = 0.f, rr1 = 0.f, rr2 = 0.f;
    if (lane < 16) {
        const int j = ((int)(unsigned int)wkey) & (NPTS - 1);
        float4 pn = pts[j];
        rr0 = pn.x - pq.x; rr1 = pn.y - pq.y; rr2 = pn.z - pq.z;
        const size_t relbase = ((size_t)(b * NPTS + q)) * (KNB * 3);
        rel[relbase + lane * 3 + 0] = rr0;
        rel[relbase + lane * 3 + 1] = rr1;
        rel[relbase + lane * 3 + 2] = rr2;
    }
    float m0 = rr0, m1 = rr1, m2 = rr2;
    float m3 = rr0 * rr0, m4 = rr0 * rr1, m5 = rr0 * rr2;
    float m6 = rr1 * rr1, m7 = rr1 * rr2, m8 = rr2 * rr2;
#pragma unroll
    for (int d = 1; d < 64; d <<= 1) {
        m0 += __shfl_xor(m0, d, 64); m1 += __shfl_xor(m1, d, 64); m2 += __shfl_xor(m2, d, 64);
        m3 += __shfl_xor(m3, d, 64); m4 += __shfl_xor(m4, d, 64); m5 += __shfl_xor(m5, d, 64);
        m6 += __shfl_xor(m6, d, 64); m7 += __shfl_xor(m7, d, 64); m8 += __shfl_xor(m8, d, 64);
    }
    if (lane == 0) {
        red9[wave][0] = m0; red9[wave][1] = m1; red9[wave][2] = m2;
        red9[wave][3] = m3; red9[wave][4] = m4; red9[wave][5] = m5;
        red9[wave][6] = m6; red9[wave][7] = m7; red9[wave][8] = m8;
    }
    __syncthreads();
    if (tid < 9)
        part1[blockIdx.x * 9 + tid] =
            red9[0][tid] + red9[1][tid] + red9[2][tid] + red9[3][tid];
}

// ---------------- K2: finalize BN1 affine + zero Gfix replicas ----------------
__global__ __launch_bounds__(256) void fin1_kernel(const float* __restrict__ part1,
                            const float* __restrict__ W1, const float* __restrict__ b1,
                            const float* __restrict__ gamma, const float* __restrict__ beta,
                            float* __restrict__ s1t1, unsigned long long* __restrict__ Gfix) {
    __shared__ double red[9][256];
    __shared__ double sm[9];
    const int t = threadIdx.x;
    double s[9] = {0, 0, 0, 0, 0, 0, 0, 0, 0};
    for (int blk = t; blk < 4096; blk += 256)
#pragma unroll
        for (int v = 0; v < 9; ++v) s[v] += (double)part1[blk * 9 + v];
#pragma unroll
    for (int v = 0; v < 9; ++v) red[v][t] = s[v];
    __syncthreads();
    // part1 fully consumed -> safe to zero Gfix (aliases part1's memory).
    for (int i = t; i < NREP * 4160; i += 256) Gfix[i] = 0ull;
    if (t < 9) {
        double x = 0.0;
        for (int i = 0; i < 256; ++i) x += red[t][i];
        sm[t] = x;
    }
    __syncthreads();
    if (t < 64) {
        const double Md = (double)M_SAMPLES;
        double mu0 = sm[0] / Md, mu1 = sm[1] / Md, mu2 = sm[2] / Md;
        double C00 = sm[3] / Md - mu0 * mu0;
        double C01 = sm[4] / Md - mu0 * mu1;
        double C02 = sm[5] / Md - mu0 * mu2;
        double C11 = sm[6] / Md - mu1 * mu1;
        double C12 = sm[7] / Md - mu1 * mu2;
        double C22 = sm[8] / Md - mu2 * mu2;
        double w0 = (double)W1[t * 3], w1 = (double)W1[t * 3 + 1], w2 = (double)W1[t * 3 + 2];
        double mean = w0 * mu0 + w1 * mu1 + w2 * mu2 + (double)b1[t];
        double var  = w0 * w0 * C00 + w1 * w1 * C11 + w2 * w2 * C22
                    + 2.0 * (w0 * w1 * C01 + w0 * w2 * C02 + w1 * w2 * C12);
        double sc = (double)gamma[t] / sqrt(var + 1e-5);
        s1t1[t]      = (float)sc;
        s1t1[64 + t] = (float)((double)beta[t] - mean * sc);
    }
}

// ---------------- K3: Gram accumulation, grid 1024, replica-split atomics --------------
__global__ __launch_bounds__(256) void gram_kernel(const float* __restrict__ rel,
        const float* __restrict__ W1, const float* __restrict__ b1,
        const float* __restrict__ s1t1, unsigned long long* __restrict__ Gfix) {
    __shared__ float  A[64][68];
    __shared__ float4 W1l[64];
    __shared__ float2 st1[64];
    const int tid = threadIdx.x;
    const int lane = tid & 63, wave = tid >> 6;
    if (tid < 64) {
        W1l[tid] = make_float4(W1[tid * 3], W1[tid * 3 + 1], W1[tid * 3 + 2], b1[tid]);
        st1[tid] = make_float2(s1t1[tid], s1t1[64 + tid]);
    }
    __syncthreads();

    const int i0 = (tid >> 4) * 4, j0 = (tid & 15) * 4;
    float g[4][4];
#pragma unroll
    for (int a = 0; a < 4; ++a)
#pragma unroll
        for (int c = 0; c < 4; ++c) g[a][c] = 0.f;
    float4 sa4[4];
#pragma unroll
    for (int i = 0; i < 4; ++i) sa4[i] = make_float4(0.f, 0.f, 0.f, 0.f);

#pragma unroll 1
    for (int ch = 0; ch < 4; ++ch) {
        const int s = (blockIdx.x * 4 + ch) * 64 + lane;
        float r0 = rel[s * 3], r1 = rel[s * 3 + 1], r2 = rel[s * 3 + 2];
#pragma unroll
        for (int i = 0; i < 4; ++i) {
            const int c0 = wave * 16 + i * 4;
            float4 av;
            {
                float4 w = W1l[c0];     float2 st = st1[c0];
                av.x = fmaxf(fmaf(st.x, (w.x * r0 + w.y * r1 + w.z * r2) + w.w, st.y), 0.f);
            }
            {
                float4 w = W1l[c0 + 1]; float2 st = st1[c0 + 1];
                av.y = fmaxf(fmaf(st.x, (w.x * r0 + w.y * r1 + w.z * r2) + w.w, st.y), 0.f);
            }
            {
                float4 w = W1l[c0 + 2]; float2 st = st1[c0 + 2];
                av.z = fmaxf(fmaf(st.x, (w.x * r0 + w.y * r1 + w.z * r2) + w.w, st.y), 0.f);
            }
            {
                float4 w = W1l[c0 + 3]; float2 st = st1[c0 + 3];
                av.w = fmaxf(fmaf(st.x, (w.x * r0 + w.y * r1 + w.z * r2) + w.w, st.y), 0.f);
            }
            *(float4*)&A[lane][c0] = av;
            sa4[i].x += av.x; sa4[i].y += av.y; sa4[i].z += av.z; sa4[i].w += av.w;
        }
        __syncthreads();
#pragma unroll 4
        for (int sl = 0; sl < 64; ++sl) {
            float4 ai = *(const float4*)&A[sl][i0];
            float4 aj = *(const float4*)&A[sl][j0];
            g[0][0] = fmaf(ai.x, aj.x, g[0][0]); g[0][1] = fmaf(ai.x, aj.y, g[0][1]);
            g[0][2] = fmaf(ai.x, aj.z, g[0][2]); g[0][3] = fmaf(ai.x, aj.w, g[0][3]);
            g[1][0] = fmaf(ai.y, aj.x, g[1][0]); g[1][1] = fmaf(ai.y, aj.y, g[1][1]);
            g[1][2] = fmaf(ai.y, aj.z, g[1][2]); g[1][3] = fmaf(ai.y, aj.w, g[1][3]);
            g[2][0] = fmaf(ai.z, aj.x, g[2][0]); g[2][1] = fmaf(ai.z, aj.y, g[2][1]);
            g[2][2] = fmaf(ai.z, aj.z, g[2][2]); g[2][3] = fmaf(ai.z, aj.w, g[2][3]);
            g[3][0] = fmaf(ai.w, aj.x, g[3][0]); g[3][1] = fmaf(ai.w, aj.y, g[3][1]);
            g[3][2] = fmaf(ai.w, aj.z, g[3][2]); g[3][3] = fmaf(ai.w, aj.w, g[3][3]);
        }
        __syncthreads();
    }
    unsigned long long* Grep = Gfix + (blockIdx.x & (NREP - 1)) * 4160;
#pragma unroll
    for (int a = 0; a < 4; ++a)
#pragma unroll
        for (int c = 0; c < 4; ++c)
            atomicAdd(&Grep[(i0 + a) * 64 + (j0 + c)],
                      (unsigned long long)((double)g[a][c] * FIXSCALE));
#pragma unroll
    for (int i = 0; i < 4; ++i) {
        float4 v = sa4[i];
#pragma unroll
        for (int d = 1; d < 64; d <<= 1) {
            v.x += __shfl_xor(v.x, d, 64); v.y += __shfl_xor(v.y, d, 64);
            v.z += __shfl_xor(v.z, d, 64); v.w += __shfl_xor(v.w, d, 64);
        }
        if (lane == 0) {
            const int c0 = wave * 16 + i * 4;
            atomicAdd(&Grep[4096 + c0 + 0], (unsigned long long)((double)v.x * FIXSCALE));
            atomicAdd(&Grep[4096 + c0 + 1], (unsigned long long)((double)v.y * FIXSCALE));
            atomicAdd(&Grep[4096 + c0 + 2], (unsigned long long)((double)v.z * FIXSCALE));
            atomicAdd(&Grep[4096 + c0 + 3], (unsigned long long)((double)v.w * FIXSCALE));
        }
    }
}

// ---------------- K4: finalize BN2 affine from G (sums NREP replicas) ----------------
__global__ __launch_bounds__(1024) void fin2G_kernel(const unsigned long long* __restrict__ Gfix,
                            const float* __restrict__ W2, const float* __restrict__ b2,
                            const float* __restrict__ gamma, const float* __restrict__ beta,
                            float* __restrict__ s2t2) {
    __shared__ float Gs[64][68];
    __shared__ float w2s[64][68];
    __shared__ float sa_s[64];
    __shared__ float red[16][64];
    const int tid = threadIdx.x;
    const double INV = 1.0 / FIXSCALE;
    for (int i = tid; i < 4096; i += 1024) {
        unsigned long long acc = 0ull;
#pragma unroll
        for (int r = 0; r < NREP; ++r) acc += Gfix[r * 4160 + i];
        Gs[i >> 6][i & 63]  = (float)((double)acc * INV);
        w2s[i >> 6][i & 63] = W2[i];
    }
    if (tid < 64) {
        unsigned long long acc = 0ull;
#pragma unroll
        for (int r = 0; r < NREP; ++r) acc += Gfix[r * 4160 + 4096 + tid];
        sa_s[tid] = (float)((double)acc * INV);
    }
    __syncthreads();

    const int o = tid & 63, part = tid >> 6;
    float partial = 0.f;
#pragma unroll
    for (int ii = 0; ii < 4; ++ii) {
        const int i = part * 4 + ii;
        float t = 0.f;
#pragma unroll
        for (int j = 0; j < 64; j += 4) {
            float4 wj = *(const float4*)&w2s[o][j];
            float4 gj = *(const float4*)&Gs[i][j];
            t = fmaf(wj.x, gj.x, t); t = fmaf(wj.y, gj.y, t);
            t = fmaf(wj.z, gj.z, t); t = fmaf(wj.w, gj.w, t);
        }
        partial = fmaf(w2s[o][i], t, partial);
    }
    red[part][o] = partial;
    __syncthreads();
    if (tid < 64) {
        double qf = 0.0;
#pragma unroll
        for (int p = 0; p < 16; ++p) qf += (double)red[p][tid];
        double SA = 0.0;
        for (int c = 0; c < 64; ++c) SA += (double)w2s[tid][c] * (double)sa_s[c];
        const double Md = (double)M_SAMPLES;
        double mean = SA / Md + (double)b2[tid];
        double var  = qf / Md - (SA / Md) * (SA / Md);
        double sc = (double)gamma[tid] / sqrt(var + 1e-5);
        s2t2[tid]      = (float)sc;
        s2t2[64 + tid] = (float)((double)beta[tid] - mean * sc);
    }
}

// ---------------- K5: block-GEMM chain + max over k (R9-verbatim, proven) --------------
#define FMA4(cv, s, wv) { cv.x = fmaf(s, wv.x, cv.x); cv.y = fmaf(s, wv.y, cv.y); \
                          cv.z = fmaf(s, wv.z, cv.z); cv.w = fmaf(s, wv.w, cv.w); }
__global__ __launch_bounds__(256) void out_kernel(const float* __restrict__ rel,
        const float* __restrict__ W1, const float* __restrict__ b1,
        const float* __restrict__ W2, const float* __restrict__ b2,
        const float* __restrict__ s1t1, const float* __restrict__ s2t2,
        float* __restrict__ out) {
    __shared__ float  W2T[64][68];
    __shared__ float  A[64][68];
    __shared__ float4 W1l[64];
    __shared__ float2 st1[64];
    __shared__ float2 st2[64];
    __shared__ float  b2l[64];
    __shared__ float  Mred[1024];

    const int tid = threadIdx.x;
    const int lane = tid & 63, wave = tid >> 6;
    const int sbase = blockIdx.x * 64;

    for (int i = tid; i < 4096; i += 256) W2T[i & 63][i >> 6] = W2[i];
    if (tid < 64) {
        W1l[tid] = make_float4(W1[tid * 3], W1[tid * 3 + 1], W1[tid * 3 + 2], b1[tid]);
        st1[tid] = make_float2(s1t1[tid], s1t1[64 + tid]);
        st2[tid] = make_float2(s2t2[tid], s2t2[64 + tid]);
        b2l[tid] = b2[tid];
    }
    const int s = sbase + lane;
    float r0 = rel[s * 3], r1 = rel[s * 3 + 1], r2 = rel[s * 3 + 2];
    __syncthreads();

#pragma unroll
    for (int i = 0; i < 4; ++i) {
        const int c0 = wave * 16 + i * 4;
        float4 av;
        {
            float4 w = W1l[c0];     float2 st = st1[c0];
            av.x = fmaxf(fmaf(st.x, (w.x * r0 + w.y * r1 + w.z * r2) + w.w, st.y), 0.f);
        }
        {
            float4 w = W1l[c0 + 1]; float2 st = st1[c0 + 1];
            av.y = fmaxf(fmaf(st.x, (w.x * r0 + w.y * r1 + w.z * r2) + w.w, st.y), 0.f);
        }
        {
            float4 w = W1l[c0 + 2]; float2 st = st1[c0 + 2];
            av.z = fmaxf(fmaf(st.x, (w.x * r0 + w.y * r1 + w.z * r2) + w.w, st.y), 0.f);
        }
        {
            float4 w = W1l[c0 + 3]; float2 st = st1[c0 + 3];
            av.w = fmaxf(fmaf(st.x, (w.x * r0 + w.y * r1 + w.z * r2) + w.w, st.y), 0.f);
        }
        *(float4*)&A[lane][c0] = av;
    }
    __syncthreads();

    const int i0 = (tid >> 4) * 4;
    const int j0 = (tid & 15) * 4;
    const float4 bj = make_float4(b2l[j0], b2l[j0 + 1], b2l[j0 + 2], b2l[j0 + 3]);

    float4 c0v = {0, 0, 0, 0}, c1v = {0, 0, 0, 0}, c2v = {0, 0, 0, 0}, c3v = {0, 0, 0, 0};
#pragma unroll
    for (int k4 = 0; k4 < 16; ++k4) {
        const int k = k4 * 4;
        float4 a0 = *(const float4*)&A[i0 + 0][k];
        float4 a1 = *(const float4*)&A[i0 + 1][k];
        float4 a2 = *(const float4*)&A[i0 + 2][k];
        float4 a3 = *(const float4*)&A[i0 + 3][k];
        float4 w0 = *(const float4*)&W2T[k + 0][j0];
        float4 w1 = *(const float4*)&W2T[k + 1][j0];
        float4 w2 = *(const float4*)&W2T[k + 2][j0];
        float4 w3 = *(const float4*)&W2T[k + 3][j0];
        FMA4(c0v, a0.x, w0) FMA4(c0v, a0.y, w1) FMA4(c0v, a0.z, w2) FMA4(c0v, a0.w, w3)
        FMA4(c1v, a1.x, w0) FMA4(c1v, a1.y, w1) FMA4(c1v, a1.z, w2) FMA4(c1v, a1.w, w3)
        FMA4(c2v, a2.x, w0) FMA4(c2v, a2.y, w1) FMA4(c2v, a2.z, w2) FMA4(c2v, a2.w, w3)
        FMA4(c3v, a3.x, w0) FMA4(c3v, a3.y, w1) FMA4(c3v, a3.z, w2) FMA4(c3v, a3.w, w3)
    }
    const float2 sA = st2[j0], sB = st2[j0 + 1], sC = st2[j0 + 2], sD = st2[j0 + 3];
#define EPI1(cv) { cv.x = fmaxf(fmaf(sA.x, cv.x + bj.x, sA.y), 0.f); \
                   cv.y = fmaxf(fmaf(sB.x, cv.y + bj.y, sB.y), 0.f); \
                   cv.z = fmaxf(fmaf(sC.x, cv.z + bj.z, sC.y), 0.f); \
                   cv.w = fmaxf(fmaf(sD.x, cv.w + bj.w, sD.y), 0.f); }
    EPI1(c0v) EPI1(c1v) EPI1(c2v) EPI1(c3v)
    __syncthreads();
    *(float4*)&A[i0 + 0][j0] = c0v;
    *(float4*)&A[i0 + 1][j0] = c1v;
    *(float4*)&A[i0 + 2][j0] = c2v;
    *(float4*)&A[i0 + 3][j0] = c3v;
    __syncthreads();

    float4 d0v = {0, 0, 0, 0}, d1v = {0, 0, 0, 0}, d2v = {0, 0, 0, 0}, d3v = {0, 0, 0, 0};
#pragma unroll
    for (int k4 = 0; k4 < 16; ++k4) {
        const int k = k4 * 4;
        float4 a0 = *(const float4*)&A[i0 + 0][k];
        float4 a1 = *(const float4*)&A[i0 + 1][k];
        float4 a2 = *(const float4*)&A[i0 + 2][k];
        float4 a3 = *(const float4*)&A[i0 + 3][k];
        float4 w0 = *(const float4*)&W2T[k + 0][j0];
        float4 w1 = *(const float4*)&W2T[k + 1][j0];
        float4 w2 = *(const float4*)&W2T[k + 2][j0];
        float4 w3 = *(const float4*)&W2T[k + 3][j0];
        FMA4(d0v, a0.x, w0) FMA4(d0v, a0.y, w1) FMA4(d0v, a0.z, w2) FMA4(d0v, a0.w, w3)
        FMA4(d1v, a1.x, w0) FMA4(d1v, a1.y, w1) FMA4(d1v, a1.z, w2) FMA4(d1v, a1.w, w3)
        FMA4(d2v, a2.x, w0) FMA4(d2v, a2.y, w1) FMA4(d2v, a2.z, w2) FMA4(d2v, a2.w, w3)
        FMA4(d3v, a3.x, w0) FMA4(d3v, a3.y, w1) FMA4(d3v, a3.z, w2) FMA4(d3v, a3.w, w3)
    }
    float4 pm;
    pm.x = fmaxf(fmaxf(d0v.x, d1v.x), fmaxf(d2v.x, d3v.x)) + bj.x;
    pm.y = fmaxf(fmaxf(d0v.y, d1v.y), fmaxf(d2v.y, d3v.y)) + bj.y;
    pm.z = fmaxf(fmaxf(d0v.z, d1v.z), fmaxf(d2v.z, d3v.z)) + bj.z;
    pm.w = fmaxf(fmaxf(d0v.w, d1v.w), fmaxf(d2v.w, d3v.w)) + bj.w;
    const int nl = i0 >> 4, dd = (i0 >> 2) & 3, jj = tid & 15;
    *(float4*)&Mred[((nl * 4 + dd) * 16 + jj) * 4] = pm;
    __syncthreads();

    {
        const int n = tid >> 6, o = tid & 63;
        float m = Mred[n * 256 + 0 * 64 + o];
        m = fmaxf(m, Mred[n * 256 + 1 * 64 + o]);
        m = fmaxf(m, Mred[n * 256 + 2 * 64 + o]);
        m = fmaxf(m, Mred[n * 256 + 3 * 64 + o]);
        const int sg = sbase + n * 16;
        const int bb = sg >> 15;
        const int nn = (sg >> 4) & (NPTS - 1);
        out[(size_t)bb * (CH * NPTS) + o * NPTS + nn] = m;
    }
}

extern "C" void kernel_launch(void* const* d_in, const int* in_sizes, int n_in,
                              void* d_out, int out_size, void* d_ws, size_t ws_size,
                              hipStream_t stream) {
    (void)in_sizes; (void)n_in; (void)out_size; (void)ws_size;
    const float* xyz   = (const float*)d_in[0];
    const float* W1    = (const float*)d_in[1];
    const float* b1    = (const float*)d_in[2];
    const float* W2    = (const float*)d_in[3];
    const float* b2    = (const float*)d_in[4];
    const float* gamma = (const float*)d_in[5];
    const float* beta  = (const float*)d_in[6];
    float* out = (float*)d_out;
    float* ws  = (float*)d_ws;

    float* rel   = ws + WS_REL;
    float* s1t1  = ws + WS_S1T1;
    float* s2t2  = ws + WS_S2T2;
    float* part1 = ws + WS_PART1;
    unsigned long long* Gfix = (unsigned long long*)(ws + WS_GFIX);  // aliases part1

    knn_rel_kernel<<<dim3(4096), dim3(256), 0, stream>>>(xyz, rel, part1);
    fin1_kernel<<<dim3(1), dim3(256), 0, stream>>>(part1, W1, b1, gamma, beta, s1t1, Gfix);
    gram_kernel<<<dim3(1024), dim3(256), 0, stream>>>(rel, W1, b1, s1t1, Gfix);
    fin2G_kernel<<<dim3(1), dim3(1024), 0, stream>>>(Gfix, W2, b2, gamma, beta, s2t2);
    out_kernel<<<dim3(4096), dim3(256), 0, stream>>>(rel, W1, b1, W2, b2, s1t1, s2t2, out);
}

// Round 11
// 245.957 us; speedup vs baseline: 1.2652x; 1.2652x over previous
//
#include <hip/hip_runtime.h>
#include <math.h>

#define BATCH 8
#define NPTS 2048
#define CH 64
#define KNB 16
#define M_SAMPLES (BATCH * NPTS * KNB)   // 262144
#define FIXSCALE 1048576.0               // 2^20 fixed-point (atomic fallback path)
#define GPART_BLKS 512

// ws layout (float offsets):
//   rel    : [0, 786432)         262144 * 3 f32
//   s1t1   : [786432, 786560)
//   s2t2   : [786560, 786688)
//   part1  : [786688, 823552)    4096*9 (knn -> fin1; dead after fin1)
//   BIG path (ws >= 11.67 MB):
//     Gpart : [786688, 2883840)  512 blocks * 4096 f32 (aliases part1)
//     sapart: [2883840, 2916608) 512 * 64 f32
//   SMALL path (fallback, proven R8):
//     Gfix  : [786688, 795008)   4160 u64 (aliases part1; zeroed in fin1)
#define WS_REL    0
#define WS_S1T1   786432
#define WS_S2T2   786560
#define WS_PART1  786688
#define WS_GFIX   786688
#define WS_GPART  786688
#define WS_SAPART 2883840
#define WS_BIG_FLOATS 2916608ull

#define SURV_CAP 192
#define D2_EPS 1e-4f

__device__ __forceinline__ unsigned long long u64min(unsigned long long a, unsigned long long b) { return a < b ? a : b; }
__device__ __forceinline__ unsigned long long u64max(unsigned long long a, unsigned long long b) { return a > b ? a : b; }

__device__ __forceinline__ unsigned long long bitonic64(unsigned long long v, int lane) {
#pragma unroll
    for (int k = 2; k <= 64; k <<= 1)
#pragma unroll
        for (int d = k >> 1; d >= 1; d >>= 1) {
            unsigned long long o = __shfl_xor(v, d, 64);
            bool keepmin = (((lane & d) == 0) == ((lane & k) == 0));
            v = keepmin ? u64min(v, o) : u64max(v, o);
        }
    return v;
}

__device__ __forceinline__ unsigned long long cand_key(const float4 pq, const float4 pj, int j, int q) {
    float dot = pq.x * pj.x + pq.y * pj.y + pq.z * pj.z;
    float d2 = fmaxf((pq.w + pj.w) - 2.0f * dot, 0.0f);
    unsigned long long key = ((unsigned long long)__float_as_uint(d2) << 32) | (unsigned int)j;
    return (j == q) ? ~0ull : key;
}

// ---------------- K1: KNN (R7-verbatim, proven) ----------------
__global__ __launch_bounds__(256) void knn_rel_kernel(const float* __restrict__ xyz,
                                                      float* __restrict__ rel,
                                                      float* __restrict__ part1) {
    __shared__ float4 pts[NPTS];
    __shared__ unsigned long long surv[4][SURV_CAP];
    __shared__ unsigned int wavecnt[4];
    __shared__ float red9[4][9];

    const int b     = blockIdx.x >> 9;
    const int qbase = (blockIdx.x & 511) * 4;
    const int tid   = threadIdx.x;
    const int wave  = tid >> 6, lane = tid & 63;

    const float* xb = xyz + (size_t)b * 3 * NPTS;
    for (int j = tid; j < NPTS; j += 256) {
        float x = xb[j], y = xb[NPTS + j], z = xb[2 * NPTS + j];
        pts[j] = make_float4(x, y, z, (x * x + y * y) + z * z);
    }
    __syncthreads();

    const int q = qbase + wave;
    const float4 pq = pts[q];

    unsigned long long lm = ~0ull;
#pragma unroll
    for (int t = 0; t < 32; ++t) {
        const int j = t * 64 + lane;
        lm = u64min(lm, cand_key(pq, pts[j], j, q));
    }
    unsigned long long sorted = bitonic64(lm, lane);
    const float Td2 = __uint_as_float((unsigned int)(__shfl(sorted, 15, 64) >> 32)) + D2_EPS;

    if (lane == 0) wavecnt[wave] = 0u;
#pragma unroll
    for (int t = 0; t < 32; ++t) {
        const int j = t * 64 + lane;
        unsigned long long key = cand_key(pq, pts[j], j, q);
        float d2 = __uint_as_float((unsigned int)(key >> 32));
        if (d2 <= Td2) {
            unsigned int pos = atomicAdd(&wavecnt[wave], 1u);
            if (pos < SURV_CAP) surv[wave][pos] = key;
        }
    }
    const unsigned int total = wavecnt[wave];

    unsigned long long wkey = ~0ull;
    bool ok = false;
    if (total >= 16u && total <= 64u) {
        unsigned long long s0 = (lane < (int)total) ? surv[wave][lane] : ~0ull;
        wkey = bitonic64(s0, lane);
        unsigned long long nxt = __shfl_down(wkey, 1, 64);
        ok = __all((lane == 63) || (wkey <= nxt)) != 0;
    }
    if (!ok) {
        unsigned long long last = 0ull; bool first = true;
#pragma unroll 1
        for (int r = 0; r < 16; ++r) {
            unsigned long long m = ~0ull;
#pragma unroll
            for (int t = 0; t < 32; ++t) {
                const int j = t * 64 + lane;
                unsigned long long key = cand_key(pq, pts[j], j, q);
                if (first || key > last) m = u64min(m, key);
            }
#pragma unroll
            for (int d = 1; d < 64; d <<= 1) m = u64min(m, __shfl_xor(m, d, 64));
            if (lane == r) wkey = m;
            last = m; first = false;
        }
    }

    float rr0 = 0.f, rr1 = 0.f, rr2 = 0.f;
    if (lane < 16) {
        const int j = ((int)(unsigned int)wkey) & (NPTS - 1);
        float4 pn = pts[j];
        rr0 = pn.x - pq.x; rr1 = pn.y - pq.y; rr2 = pn.z - pq.z;
        const size_t relbase = ((size_t)(b * NPTS + q)) * (KNB * 3);
        rel[relbase + lane * 3 + 0] = rr0;
        rel[relbase + lane * 3 + 1] = rr1;
        rel[relbase + lane * 3 + 2] = rr2;
    }
    float m0 = rr0, m1 = rr1, m2 = rr2;
    float m3 = rr0 * rr0, m4 = rr0 * rr1, m5 = rr0 * rr2;
    float m6 = rr1 * rr1, m7 = rr1 * rr2, m8 = rr2 * rr2;
#pragma unroll
    for (int d = 1; d < 64; d <<= 1) {
        m0 += __shfl_xor(m0, d, 64); m1 += __shfl_xor(m1, d, 64); m2 += __shfl_xor(m2, d, 64);
        m3 += __shfl_xor(m3, d, 64); m4 += __shfl_xor(m4, d, 64); m5 += __shfl_xor(m5, d, 64);
        m6 += __shfl_xor(m6, d, 64); m7 += __shfl_xor(m7, d, 64); m8 += __shfl_xor(m8, d, 64);
    }
    if (lane == 0) {
        red9[wave][0] = m0; red9[wave][1] = m1; red9[wave][2] = m2;
        red9[wave][3] = m3; red9[wave][4] = m4; red9[wave][5] = m5;
        red9[wave][6] = m6; red9[wave][7] = m7; red9[wave][8] = m8;
    }
    __syncthreads();
    if (tid < 9)
        part1[blockIdx.x * 9 + tid] =
            red9[0][tid] + red9[1][tid] + red9[2][tid] + red9[3][tid];
}

// ---------------- K2: finalize BN1 affine (+ zero Gfix; harmless in big path) ----------
__global__ __launch_bounds__(256) void fin1_kernel(const float* __restrict__ part1,
                            const float* __restrict__ W1, const float* __restrict__ b1,
                            const float* __restrict__ gamma, const float* __restrict__ beta,
                            float* __restrict__ s1t1, unsigned long long* __restrict__ Gfix) {
    __shared__ double red[9][256];
    __shared__ double sm[9];
    const int t = threadIdx.x;
    double s[9] = {0, 0, 0, 0, 0, 0, 0, 0, 0};
    for (int blk = t; blk < 4096; blk += 256)
#pragma unroll
        for (int v = 0; v < 9; ++v) s[v] += (double)part1[blk * 9 + v];
#pragma unroll
    for (int v = 0; v < 9; ++v) red[v][t] = s[v];
    __syncthreads();
    // part1 fully consumed above -> safe to zero the aliased Gfix region.
    for (int i = t; i < 4160; i += 256) Gfix[i] = 0ull;
    if (t < 9) {
        double x = 0.0;
        for (int i = 0; i < 256; ++i) x += red[t][i];
        sm[t] = x;
    }
    __syncthreads();
    if (t < 64) {
        const double Md = (double)M_SAMPLES;
        double mu0 = sm[0] / Md, mu1 = sm[1] / Md, mu2 = sm[2] / Md;
        double C00 = sm[3] / Md - mu0 * mu0;
        double C01 = sm[4] / Md - mu0 * mu1;
        double C02 = sm[5] / Md - mu0 * mu2;
        double C11 = sm[6] / Md - mu1 * mu1;
        double C12 = sm[7] / Md - mu1 * mu2;
        double C22 = sm[8] / Md - mu2 * mu2;
        double w0 = (double)W1[t * 3], w1 = (double)W1[t * 3 + 1], w2 = (double)W1[t * 3 + 2];
        double mean = w0 * mu0 + w1 * mu1 + w2 * mu2 + (double)b1[t];
        double var  = w0 * w0 * C00 + w1 * w1 * C11 + w2 * w2 * C22
                    + 2.0 * (w0 * w1 * C01 + w0 * w2 * C02 + w1 * w2 * C12);
        double sc = (double)gamma[t] / sqrt(var + 1e-5);
        s1t1[t]      = (float)sc;
        s1t1[64 + t] = (float)((double)beta[t] - mean * sc);
    }
}

// ======== shared gram body: computes per-block G partial in registers ========
// lane = sample, wave = 16-channel block; thread (i0,j0) owns a 4x4 G tile.
#define GRAM_BODY(NCHUNK)                                                         \
    __shared__ float  A[64][68];                                                  \
    __shared__ float4 W1l[64];                                                    \
    __shared__ float2 st1[64];                                                    \
    const int tid = threadIdx.x;                                                  \
    const int lane = tid & 63, wave = tid >> 6;                                   \
    if (tid < 64) {                                                               \
        W1l[tid] = make_float4(W1[tid * 3], W1[tid * 3 + 1], W1[tid * 3 + 2], b1[tid]); \
        st1[tid] = make_float2(s1t1[tid], s1t1[64 + tid]);                        \
    }                                                                             \
    __syncthreads();                                                              \
    const int i0 = (tid >> 4) * 4, j0 = (tid & 15) * 4;                           \
    float g[4][4];                                                                \
    _Pragma("unroll")                                                             \
    for (int a = 0; a < 4; ++a)                                                   \
        _Pragma("unroll")                                                         \
        for (int c = 0; c < 4; ++c) g[a][c] = 0.f;                                \
    float4 sa4[4];                                                                \
    _Pragma("unroll")                                                             \
    for (int i = 0; i < 4; ++i) sa4[i] = make_float4(0.f, 0.f, 0.f, 0.f);         \
    _Pragma("unroll 1")                                                           \
    for (int ch = 0; ch < NCHUNK; ++ch) {                                         \
        const int s = (blockIdx.x * NCHUNK + ch) * 64 + lane;                     \
        float r0 = rel[s * 3], r1 = rel[s * 3 + 1], r2 = rel[s * 3 + 2];          \
        _Pragma("unroll")                                                         \
        for (int i = 0; i < 4; ++i) {                                             \
            const int c0 = wave * 16 + i * 4;                                     \
            float4 av;                                                            \
            { float4 w = W1l[c0];     float2 st = st1[c0];                        \
              av.x = fmaxf(fmaf(st.x, (w.x*r0 + w.y*r1 + w.z*r2) + w.w, st.y), 0.f); } \
            { float4 w = W1l[c0 + 1]; float2 st = st1[c0 + 1];                    \
              av.y = fmaxf(fmaf(st.x, (w.x*r0 + w.y*r1 + w.z*r2) + w.w, st.y), 0.f); } \
            { float4 w = W1l[c0 + 2]; float2 st = st1[c0 + 2];                    \
              av.z = fmaxf(fmaf(st.x, (w.x*r0 + w.y*r1 + w.z*r2) + w.w, st.y), 0.f); } \
            { float4 w = W1l[c0 + 3]; float2 st = st1[c0 + 3];                    \
              av.w = fmaxf(fmaf(st.x, (w.x*r0 + w.y*r1 + w.z*r2) + w.w, st.y), 0.f); } \
            *(float4*)&A[lane][c0] = av;                                          \
            sa4[i].x += av.x; sa4[i].y += av.y; sa4[i].z += av.z; sa4[i].w += av.w; \
        }                                                                         \
        __syncthreads();                                                          \
        _Pragma("unroll 4")                                                       \
        for (int sl = 0; sl < 64; ++sl) {                                         \
            float4 ai = *(const float4*)&A[sl][i0];                               \
            float4 aj = *(const float4*)&A[sl][j0];                               \
            g[0][0] = fmaf(ai.x, aj.x, g[0][0]); g[0][1] = fmaf(ai.x, aj.y, g[0][1]); \
            g[0][2] = fmaf(ai.x, aj.z, g[0][2]); g[0][3] = fmaf(ai.x, aj.w, g[0][3]); \
            g[1][0] = fmaf(ai.y, aj.x, g[1][0]); g[1][1] = fmaf(ai.y, aj.y, g[1][1]); \
            g[1][2] = fmaf(ai.y, aj.z, g[1][2]); g[1][3] = fmaf(ai.y, aj.w, g[1][3]); \
            g[2][0] = fmaf(ai.z, aj.x, g[2][0]); g[2][1] = fmaf(ai.z, aj.y, g[2][1]); \
            g[2][2] = fmaf(ai.z, aj.z, g[2][2]); g[2][3] = fmaf(ai.z, aj.w, g[2][3]); \
            g[3][0] = fmaf(ai.w, aj.x, g[3][0]); g[3][1] = fmaf(ai.w, aj.y, g[3][1]); \
            g[3][2] = fmaf(ai.w, aj.z, g[3][2]); g[3][3] = fmaf(ai.w, aj.w, g[3][3]); \
        }                                                                         \
        __syncthreads();                                                          \
    }                                                                             \
    _Pragma("unroll")                                                             \
    for (int i = 0; i < 4; ++i) {                                                 \
        float4 v = sa4[i];                                                        \
        _Pragma("unroll")                                                         \
        for (int d = 1; d < 64; d <<= 1) {                                        \
            v.x += __shfl_xor(v.x, d, 64); v.y += __shfl_xor(v.y, d, 64);         \
            v.z += __shfl_xor(v.z, d, 64); v.w += __shfl_xor(v.w, d, 64);         \
        }                                                                         \
        sa4[i] = v;                                                               \
    }

// ---------------- K3a (BIG): per-block partials, no atomics ----------------
// grid 512, block 256, 8 chunks/block; coalesced float4 stores.
__global__ __launch_bounds__(256) void gram_part_kernel(const float* __restrict__ rel,
        const float* __restrict__ W1, const float* __restrict__ b1,
        const float* __restrict__ s1t1,
        float* __restrict__ Gpart, float* __restrict__ sapart) {
    GRAM_BODY(8)
    float* Gp = Gpart + (size_t)blockIdx.x * 4096;
#pragma unroll
    for (int a = 0; a < 4; ++a)
        *(float4*)&Gp[(i0 + a) * 64 + j0] = make_float4(g[a][0], g[a][1], g[a][2], g[a][3]);
    if (lane == 0) {
        float* sp = sapart + (size_t)blockIdx.x * 64 + wave * 16;
#pragma unroll
        for (int i = 0; i < 4; ++i) *(float4*)&sp[i * 4] = sa4[i];
    }
}

// ---------------- K3b (SMALL fallback, proven R8): fixed-point atomics ------------
__global__ __launch_bounds__(256) void gram_atomic_kernel(const float* __restrict__ rel,
        const float* __restrict__ W1, const float* __restrict__ b1,
        const float* __restrict__ s1t1, unsigned long long* __restrict__ Gfix) {
    GRAM_BODY(16)
#pragma unroll
    for (int a = 0; a < 4; ++a)
#pragma unroll
        for (int c = 0; c < 4; ++c)
            atomicAdd(&Gfix[(i0 + a) * 64 + (j0 + c)],
                      (unsigned long long)((double)g[a][c] * FIXSCALE));
    if (lane == 0) {
#pragma unroll
        for (int i = 0; i < 4; ++i) {
            const int c0 = wave * 16 + i * 4;
            atomicAdd(&Gfix[4096 + c0 + 0], (unsigned long long)((double)sa4[i].x * FIXSCALE));
            atomicAdd(&Gfix[4096 + c0 + 1], (unsigned long long)((double)sa4[i].y * FIXSCALE));
            atomicAdd(&Gfix[4096 + c0 + 2], (unsigned long long)((double)sa4[i].z * FIXSCALE));
            atomicAdd(&Gfix[4096 + c0 + 3], (unsigned long long)((double)sa4[i].w * FIXSCALE));
        }
    }
}

// ======== shared fin2G tail: s2t2 from Gs/w2s/sa_s in LDS ========
#define FIN2G_TAIL                                                                \
    const int o = tid & 63, part = tid >> 6;                                      \
    float partial = 0.f;                                                          \
    _Pragma("unroll")                                                             \
    for (int ii = 0; ii < 4; ++ii) {                                              \
        const int i = part * 4 + ii;                                              \
        float t2 = 0.f;                                                           \
        _Pragma("unroll")                                                         \
        for (int j = 0; j < 64; j += 4) {                                         \
            float4 wj = *(const float4*)&w2s[o][j];                               \
            float4 gj = *(const float4*)&Gs[i][j];                                \
            t2 = fmaf(wj.x, gj.x, t2); t2 = fmaf(wj.y, gj.y, t2);                 \
            t2 = fmaf(wj.z, gj.z, t2); t2 = fmaf(wj.w, gj.w, t2);                 \
        }                                                                         \
        partial = fmaf(w2s[o][i], t2, partial);                                   \
    }                                                                             \
    red[part][o] = partial;                                                       \
    __syncthreads();                                                              \
    if (tid < 64) {                                                               \
        double qf = 0.0;                                                          \
        _Pragma("unroll")                                                         \
        for (int p = 0; p < 16; ++p) qf += (double)red[p][tid];                   \
        double SA = 0.0;                                                          \
        for (int c = 0; c < 64; ++c) SA += (double)w2s[tid][c] * (double)sa_s[c]; \
        const double Md = (double)M_SAMPLES;                                      \
        double mean = SA / Md + (double)b2[tid];                                  \
        double var  = qf / Md - (SA / Md) * (SA / Md);                            \
        double sc = (double)gamma[tid] / sqrt(var + 1e-5);                        \
        s2t2[tid]      = (float)sc;                                               \
        s2t2[64 + tid] = (float)((double)beta[tid] - mean * sc);                  \
    }

// ---------------- K4a (BIG): f64 fixed-order partial reduction ----------------
__global__ __launch_bounds__(1024) void fin2G_part_kernel(const float* __restrict__ Gpart,
                            const float* __restrict__ sapart,
                            const float* __restrict__ W2, const float* __restrict__ b2,
                            const float* __restrict__ gamma, const float* __restrict__ beta,
                            float* __restrict__ s2t2) {
    __shared__ float Gs[64][68];
    __shared__ float w2s[64][68];
    __shared__ float sa_s[64];
    __shared__ float red[16][64];
    const int tid = threadIdx.x;
    for (int i = tid; i < 4096; i += 1024) {
        double acc = 0.0;
        for (int p = 0; p < GPART_BLKS; ++p) acc += (double)Gpart[(size_t)p * 4096 + i];
        Gs[i >> 6][i & 63]  = (float)acc;
        w2s[i >> 6][i & 63] = W2[i];
    }
    if (tid < 64) {
        double acc = 0.0;
        for (int p = 0; p < GPART_BLKS; ++p) acc += (double)sapart[(size_t)p * 64 + tid];
        sa_s[tid] = (float)acc;
    }
    __syncthreads();
    FIN2G_TAIL
}

// ---------------- K4b (SMALL fallback, proven R8) ----------------
__global__ __launch_bounds__(1024) void fin2G_atomic_kernel(const unsigned long long* __restrict__ Gfix,
                            const float* __restrict__ W2, const float* __restrict__ b2,
                            const float* __restrict__ gamma, const float* __restrict__ beta,
                            float* __restrict__ s2t2) {
    __shared__ float Gs[64][68];
    __shared__ float w2s[64][68];
    __shared__ float sa_s[64];
    __shared__ float red[16][64];
    const int tid = threadIdx.x;
    const double INV = 1.0 / FIXSCALE;
    for (int i = tid; i < 4096; i += 1024) {
        Gs[i >> 6][i & 63]  = (float)((double)Gfix[i] * INV);
        w2s[i >> 6][i & 63] = W2[i];
    }
    if (tid < 64) sa_s[tid] = (float)((double)Gfix[4096 + tid] * INV);
    __syncthreads();
    FIN2G_TAIL
}

// ---------------- K5: block-GEMM chain + max over k (R9-verbatim, proven) --------------
#define FMA4(cv, s, wv) { cv.x = fmaf(s, wv.x, cv.x); cv.y = fmaf(s, wv.y, cv.y); \
                          cv.z = fmaf(s, wv.z, cv.z); cv.w = fmaf(s, wv.w, cv.w); }
__global__ __launch_bounds__(256) void out_kernel(const float* __restrict__ rel,
        const float* __restrict__ W1, const float* __restrict__ b1,
        const float* __restrict__ W2, const float* __restrict__ b2,
        const float* __restrict__ s1t1, const float* __restrict__ s2t2,
        float* __restrict__ out) {
    __shared__ float  W2T[64][68];
    __shared__ float  A[64][68];
    __shared__ float4 W1l[64];
    __shared__ float2 st1[64];
    __shared__ float2 st2[64];
    __shared__ float  b2l[64];
    __shared__ float  Mred[1024];

    const int tid = threadIdx.x;
    const int lane = tid & 63, wave = tid >> 6;
    const int sbase = blockIdx.x * 64;

    for (int i = tid; i < 4096; i += 256) W2T[i & 63][i >> 6] = W2[i];
    if (tid < 64) {
        W1l[tid] = make_float4(W1[tid * 3], W1[tid * 3 + 1], W1[tid * 3 + 2], b1[tid]);
        st1[tid] = make_float2(s1t1[tid], s1t1[64 + tid]);
        st2[tid] = make_float2(s2t2[tid], s2t2[64 + tid]);
        b2l[tid] = b2[tid];
    }
    const int s = sbase + lane;
    float r0 = rel[s * 3], r1 = rel[s * 3 + 1], r2 = rel[s * 3 + 2];
    __syncthreads();

#pragma unroll
    for (int i = 0; i < 4; ++i) {
        const int c0 = wave * 16 + i * 4;
        float4 av;
        {
            float4 w = W1l[c0];     float2 st = st1[c0];
            av.x = fmaxf(fmaf(st.x, (w.x * r0 + w.y * r1 + w.z * r2) + w.w, st.y), 0.f);
        }
        {
            float4 w = W1l[c0 + 1]; float2 st = st1[c0 + 1];
            av.y = fmaxf(fmaf(st.x, (w.x * r0 + w.y * r1 + w.z * r2) + w.w, st.y), 0.f);
        }
        {
            float4 w = W1l[c0 + 2]; float2 st = st1[c0 + 2];
            av.z = fmaxf(fmaf(st.x, (w.x * r0 + w.y * r1 + w.z * r2) + w.w, st.y), 0.f);
        }
        {
            float4 w = W1l[c0 + 3]; float2 st = st1[c0 + 3];
            av.w = fmaxf(fmaf(st.x, (w.x * r0 + w.y * r1 + w.z * r2) + w.w, st.y), 0.f);
        }
        *(float4*)&A[lane][c0] = av;
    }
    __syncthreads();

    const int i0 = (tid >> 4) * 4;
    const int j0 = (tid & 15) * 4;
    const float4 bj = make_float4(b2l[j0], b2l[j0 + 1], b2l[j0 + 2], b2l[j0 + 3]);

    float4 c0v = {0, 0, 0, 0}, c1v = {0, 0, 0, 0}, c2v = {0, 0, 0, 0}, c3v = {0, 0, 0, 0};
#pragma unroll
    for (int k4 = 0; k4 < 16; ++k4) {
        const int k = k4 * 4;
        float4 a0 = *(const float4*)&A[i0 + 0][k];
        float4 a1 = *(const float4*)&A[i0 + 1][k];
        float4 a2 = *(const float4*)&A[i0 + 2][k];
        float4 a3 = *(const float4*)&A[i0 + 3][k];
        float4 w0 = *(const float4*)&W2T[k + 0][j0];
        float4 w1 = *(const float4*)&W2T[k + 1][j0];
        float4 w2 = *(const float4*)&W2T[k + 2][j0];
        float4 w3 = *(const float4*)&W2T[k + 3][j0];
        FMA4(c0v, a0.x, w0) FMA4(c0v, a0.y, w1) FMA4(c0v, a0.z, w2) FMA4(c0v, a0.w, w3)
        FMA4(c1v, a1.x, w0) FMA4(c1v, a1.y, w1) FMA4(c1v, a1.z, w2) FMA4(c1v, a1.w, w3)
        FMA4(c2v, a2.x, w0) FMA4(c2v, a2.y, w1) FMA4(c2v, a2.z, w2) FMA4(c2v, a2.w, w3)
        FMA4(c3v, a3.x, w0) FMA4(c3v, a3.y, w1) FMA4(c3v, a3.z, w2) FMA4(c3v, a3.w, w3)
    }
    const float2 sA = st2[j0], sB = st2[j0 + 1], sC = st2[j0 + 2], sD = st2[j0 + 3];
#define EPI1(cv) { cv.x = fmaxf(fmaf(sA.x, cv.x + bj.x, sA.y), 0.f); \
                   cv.y = fmaxf(fmaf(sB.x, cv.y + bj.y, sB.y), 0.f); \
                   cv.z = fmaxf(fmaf(sC.x, cv.z + bj.z, sC.y), 0.f); \
                   cv.w = fmaxf(fmaf(sD.x, cv.w + bj.w, sD.y), 0.f); }
    EPI1(c0v) EPI1(c1v) EPI1(c2v) EPI1(c3v)
    __syncthreads();
    *(float4*)&A[i0 + 0][j0] = c0v;
    *(float4*)&A[i0 + 1][j0] = c1v;
    *(float4*)&A[i0 + 2][j0] = c2v;
    *(float4*)&A[i0 + 3][j0] = c3v;
    __syncthreads();

    float4 d0v = {0, 0, 0, 0}, d1v = {0, 0, 0, 0}, d2v = {0, 0, 0, 0}, d3v = {0, 0, 0, 0};
#pragma unroll
    for (int k4 = 0; k4 < 16; ++k4) {
        const int k = k4 * 4;
        float4 a0 = *(const float4*)&A[i0 + 0][k];
        float4 a1 = *(const float4*)&A[i0 + 1][k];
        float4 a2 = *(const float4*)&A[i0 + 2][k];
        float4 a3 = *(const float4*)&A[i0 + 3][k];
        float4 w0 = *(const float4*)&W2T[k + 0][j0];
        float4 w1 = *(const float4*)&W2T[k + 1][j0];
        float4 w2 = *(const float4*)&W2T[k + 2][j0];
        float4 w3 = *(const float4*)&W2T[k + 3][j0];
        FMA4(d0v, a0.x, w0) FMA4(d0v, a0.y, w1) FMA4(d0v, a0.z, w2) FMA4(d0v, a0.w, w3)
        FMA4(d1v, a1.x, w0) FMA4(d1v, a1.y, w1) FMA4(d1v, a1.z, w2) FMA4(d1v, a1.w, w3)
        FMA4(d2v, a2.x, w0) FMA4(d2v, a2.y, w1) FMA4(d2v, a2.z, w2) FMA4(d2v, a2.w, w3)
        FMA4(d3v, a3.x, w0) FMA4(d3v, a3.y, w1) FMA4(d3v, a3.z, w2) FMA4(d3v, a3.w, w3)
    }
    float4 pm;
    pm.x = fmaxf(fmaxf(d0v.x, d1v.x), fmaxf(d2v.x, d3v.x)) + bj.x;
    pm.y = fmaxf(fmaxf(d0v.y, d1v.y), fmaxf(d2v.y, d3v.y)) + bj.y;
    pm.z = fmaxf(fmaxf(d0v.z, d1v.z), fmaxf(d2v.z, d3v.z)) + bj.z;
    pm.w = fmaxf(fmaxf(d0v.w, d1v.w), fmaxf(d2v.w, d3v.w)) + bj.w;
    const int nl = i0 >> 4, dd = (i0 >> 2) & 3, jj = tid & 15;
    *(float4*)&Mred[((nl * 4 + dd) * 16 + jj) * 4] = pm;
    __syncthreads();

    {
        const int n = tid >> 6, o = tid & 63;
        float m = Mred[n * 256 + 0 * 64 + o];
        m = fmaxf(m, Mred[n * 256 + 1 * 64 + o]);
        m = fmaxf(m, Mred[n * 256 + 2 * 64 + o]);
        m = fmaxf(m, Mred[n * 256 + 3 * 64 + o]);
        const int sg = sbase + n * 16;
        const int bb = sg >> 15;
        const int nn = (sg >> 4) & (NPTS - 1);
        out[(size_t)bb * (CH * NPTS) + o * NPTS + nn] = m;
    }
}

extern "C" void kernel_launch(void* const* d_in, const int* in_sizes, int n_in,
                              void* d_out, int out_size, void* d_ws, size_t ws_size,
                              hipStream_t stream) {
    (void)in_sizes; (void)n_in; (void)out_size;
    const float* xyz   = (const float*)d_in[0];
    const float* W1    = (const float*)d_in[1];
    const float* b1    = (const float*)d_in[2];
    const float* W2    = (const float*)d_in[3];
    const float* b2    = (const float*)d_in[4];
    const float* gamma = (const float*)d_in[5];
    const float* beta  = (const float*)d_in[6];
    float* out = (float*)d_out;
    float* ws  = (float*)d_ws;

    float* rel    = ws + WS_REL;
    float* s1t1   = ws + WS_S1T1;
    float* s2t2   = ws + WS_S2T2;
    float* part1  = ws + WS_PART1;
    float* Gpart  = ws + WS_GPART;
    float* sapart = ws + WS_SAPART;
    unsigned long long* Gfix = (unsigned long long*)(ws + WS_GFIX);

    // ws_size is constant across calls -> branch is deterministic / capture-safe.
    const bool big = ws_size >= WS_BIG_FLOATS * 4ull;

    knn_rel_kernel<<<dim3(4096), dim3(256), 0, stream>>>(xyz, rel, part1);
    fin1_kernel<<<dim3(1), dim3(256), 0, stream>>>(part1, W1, b1, gamma, beta, s1t1, Gfix);
    if (big) {
        gram_part_kernel<<<dim3(GPART_BLKS), dim3(256), 0, stream>>>(rel, W1, b1, s1t1, Gpart, sapart);
        fin2G_part_kernel<<<dim3(1), dim3(1024), 0, stream>>>(Gpart, sapart, W2, b2, gamma, beta, s2t2);
    } else {
        gram_atomic_kernel<<<dim3(256), dim3(256), 0, stream>>>(rel, W1, b1, s1t1, Gfix);
        fin2G_atomic_kernel<<<dim3(1), dim3(1024), 0, stream>>>(Gfix, W2, b2, gamma, beta, s2t2);
    }
    out_kernel<<<dim3(4096), dim3(256), 0, stream>>>(rel, W1, b1, W2, b2, s1t1, s2t2, out);
}

// Round 12
// 168.826 us; speedup vs baseline: 1.8432x; 1.4569x over previous
//
#include <hip/hip_runtime.h>
#include <math.h>

#define BATCH 8
#define NPTS 2048
#define CH 64
#define KNB 16
#define M_SAMPLES (BATCH * NPTS * KNB)   // 262144
#define FIXSCALE 1048576.0               // 2^20 fixed-point (atomic fallback path)
#define GPART_BLKS 512

// ws layout (float offsets) — IDENTICAL to R11:
//   rel    : [0, 786432)         262144 * 3 f32
//   s1t1   : [786432, 786560)
//   s2t2   : [786560, 786688)
//   part1  : [786688, 823552)    4096*9 (knn -> fin1; dead after fin1)
//   BIG path (ws >= 11.67 MB):
//     Gpart : [786688, 2883840)  512 blocks * 4096 f32 (aliases part1)
//     sapart: [2883840, 2916608) 512 * 64 f32
//     (gred_kernel reduces all 512 partials INTO row 511 in-place)
//   SMALL path (fallback, proven R8):
//     Gfix  : [786688, 795008)   4160 u64 (aliases part1; zeroed in fin1)
#define WS_REL    0
#define WS_S1T1   786432
#define WS_S2T2   786560
#define WS_PART1  786688
#define WS_GFIX   786688
#define WS_GPART  786688
#define WS_SAPART 2883840
#define WS_BIG_FLOATS 2916608ull

#define SURV_CAP 192
#define D2_EPS 1e-4f

__device__ __forceinline__ unsigned long long u64min(unsigned long long a, unsigned long long b) { return a < b ? a : b; }
__device__ __forceinline__ unsigned long long u64max(unsigned long long a, unsigned long long b) { return a > b ? a : b; }

__device__ __forceinline__ unsigned long long bitonic64(unsigned long long v, int lane) {
#pragma unroll
    for (int k = 2; k <= 64; k <<= 1)
#pragma unroll
        for (int d = k >> 1; d >= 1; d >>= 1) {
            unsigned long long o = __shfl_xor(v, d, 64);
            bool keepmin = (((lane & d) == 0) == ((lane & k) == 0));
            v = keepmin ? u64min(v, o) : u64max(v, o);
        }
    return v;
}

__device__ __forceinline__ unsigned long long cand_key(const float4 pq, const float4 pj, int j, int q) {
    float dot = pq.x * pj.x + pq.y * pj.y + pq.z * pj.z;
    float d2 = fmaxf((pq.w + pj.w) - 2.0f * dot, 0.0f);
    unsigned long long key = ((unsigned long long)__float_as_uint(d2) << 32) | (unsigned int)j;
    return (j == q) ? ~0ull : key;
}

// ---------------- K1: KNN (R7-verbatim, proven) ----------------
__global__ __launch_bounds__(256) void knn_rel_kernel(const float* __restrict__ xyz,
                                                      float* __restrict__ rel,
                                                      float* __restrict__ part1) {
    __shared__ float4 pts[NPTS];
    __shared__ unsigned long long surv[4][SURV_CAP];
    __shared__ unsigned int wavecnt[4];
    __shared__ float red9[4][9];

    const int b     = blockIdx.x >> 9;
    const int qbase = (blockIdx.x & 511) * 4;
    const int tid   = threadIdx.x;
    const int wave  = tid >> 6, lane = tid & 63;

    const float* xb = xyz + (size_t)b * 3 * NPTS;
    for (int j = tid; j < NPTS; j += 256) {
        float x = xb[j], y = xb[NPTS + j], z = xb[2 * NPTS + j];
        pts[j] = make_float4(x, y, z, (x * x + y * y) + z * z);
    }
    __syncthreads();

    const int q = qbase + wave;
    const float4 pq = pts[q];

    unsigned long long lm = ~0ull;
#pragma unroll
    for (int t = 0; t < 32; ++t) {
        const int j = t * 64 + lane;
        lm = u64min(lm, cand_key(pq, pts[j], j, q));
    }
    unsigned long long sorted = bitonic64(lm, lane);
    const float Td2 = __uint_as_float((unsigned int)(__shfl(sorted, 15, 64) >> 32)) + D2_EPS;

    if (lane == 0) wavecnt[wave] = 0u;
#pragma unroll
    for (int t = 0; t < 32; ++t) {
        const int j = t * 64 + lane;
        unsigned long long key = cand_key(pq, pts[j], j, q);
        float d2 = __uint_as_float((unsigned int)(key >> 32));
        if (d2 <= Td2) {
            unsigned int pos = atomicAdd(&wavecnt[wave], 1u);
            if (pos < SURV_CAP) surv[wave][pos] = key;
        }
    }
    const unsigned int total = wavecnt[wave];

    unsigned long long wkey = ~0ull;
    bool ok = false;
    if (total >= 16u && total <= 64u) {
        unsigned long long s0 = (lane < (int)total) ? surv[wave][lane] : ~0ull;
        wkey = bitonic64(s0, lane);
        unsigned long long nxt = __shfl_down(wkey, 1, 64);
        ok = __all((lane == 63) || (wkey <= nxt)) != 0;
    }
    if (!ok) {
        unsigned long long last = 0ull; bool first = true;
#pragma unroll 1
        for (int r = 0; r < 16; ++r) {
            unsigned long long m = ~0ull;
#pragma unroll
            for (int t = 0; t < 32; ++t) {
                const int j = t * 64 + lane;
                unsigned long long key = cand_key(pq, pts[j], j, q);
                if (first || key > last) m = u64min(m, key);
            }
#pragma unroll
            for (int d = 1; d < 64; d <<= 1) m = u64min(m, __shfl_xor(m, d, 64));
            if (lane == r) wkey = m;
            last = m; first = false;
        }
    }

    float rr0 = 0.f, rr1 = 0.f, rr2 = 0.f;
    if (lane < 16) {
        const int j = ((int)(unsigned int)wkey) & (NPTS - 1);
        float4 pn = pts[j];
        rr0 = pn.x - pq.x; rr1 = pn.y - pq.y; rr2 = pn.z - pq.z;
        const size_t relbase = ((size_t)(b * NPTS + q)) * (KNB * 3);
        rel[relbase + lane * 3 + 0] = rr0;
        rel[relbase + lane * 3 + 1] = rr1;
        rel[relbase + lane * 3 + 2] = rr2;
    }
    float m0 = rr0, m1 = rr1, m2 = rr2;
    float m3 = rr0 * rr0, m4 = rr0 * rr1, m5 = rr0 * rr2;
    float m6 = rr1 * rr1, m7 = rr1 * rr2, m8 = rr2 * rr2;
#pragma unroll
    for (int d = 1; d < 64; d <<= 1) {
        m0 += __shfl_xor(m0, d, 64); m1 += __shfl_xor(m1, d, 64); m2 += __shfl_xor(m2, d, 64);
        m3 += __shfl_xor(m3, d, 64); m4 += __shfl_xor(m4, d, 64); m5 += __shfl_xor(m5, d, 64);
        m6 += __shfl_xor(m6, d, 64); m7 += __shfl_xor(m7, d, 64); m8 += __shfl_xor(m8, d, 64);
    }
    if (lane == 0) {
        red9[wave][0] = m0; red9[wave][1] = m1; red9[wave][2] = m2;
        red9[wave][3] = m3; red9[wave][4] = m4; red9[wave][5] = m5;
        red9[wave][6] = m6; red9[wave][7] = m7; red9[wave][8] = m8;
    }
    __syncthreads();
    if (tid < 9)
        part1[blockIdx.x * 9 + tid] =
            red9[0][tid] + red9[1][tid] + red9[2][tid] + red9[3][tid];
}

// ---------------- K2: finalize BN1 affine (+ zero Gfix; harmless in big path) ----------
__global__ __launch_bounds__(256) void fin1_kernel(const float* __restrict__ part1,
                            const float* __restrict__ W1, const float* __restrict__ b1,
                            const float* __restrict__ gamma, const float* __restrict__ beta,
                            float* __restrict__ s1t1, unsigned long long* __restrict__ Gfix) {
    __shared__ double red[9][256];
    __shared__ double sm[9];
    const int t = threadIdx.x;
    double s[9] = {0, 0, 0, 0, 0, 0, 0, 0, 0};
    for (int blk = t; blk < 4096; blk += 256)
#pragma unroll
        for (int v = 0; v < 9; ++v) s[v] += (double)part1[blk * 9 + v];
#pragma unroll
    for (int v = 0; v < 9; ++v) red[v][t] = s[v];
    __syncthreads();
    for (int i = t; i < 4160; i += 256) Gfix[i] = 0ull;
    if (t < 9) {
        double x = 0.0;
        for (int i = 0; i < 256; ++i) x += red[t][i];
        sm[t] = x;
    }
    __syncthreads();
    if (t < 64) {
        const double Md = (double)M_SAMPLES;
        double mu0 = sm[0] / Md, mu1 = sm[1] / Md, mu2 = sm[2] / Md;
        double C00 = sm[3] / Md - mu0 * mu0;
        double C01 = sm[4] / Md - mu0 * mu1;
        double C02 = sm[5] / Md - mu0 * mu2;
        double C11 = sm[6] / Md - mu1 * mu1;
        double C12 = sm[7] / Md - mu1 * mu2;
        double C22 = sm[8] / Md - mu2 * mu2;
        double w0 = (double)W1[t * 3], w1 = (double)W1[t * 3 + 1], w2 = (double)W1[t * 3 + 2];
        double mean = w0 * mu0 + w1 * mu1 + w2 * mu2 + (double)b1[t];
        double var  = w0 * w0 * C00 + w1 * w1 * C11 + w2 * w2 * C22
                    + 2.0 * (w0 * w1 * C01 + w0 * w2 * C02 + w1 * w2 * C12);
        double sc = (double)gamma[t] / sqrt(var + 1e-5);
        s1t1[t]      = (float)sc;
        s1t1[64 + t] = (float)((double)beta[t] - mean * sc);
    }
}

// ======== shared gram body (R11-verbatim) ========
#define GRAM_BODY(NCHUNK)                                                         \
    __shared__ float  A[64][68];                                                  \
    __shared__ float4 W1l[64];                                                    \
    __shared__ float2 st1[64];                                                    \
    const int tid = threadIdx.x;                                                  \
    const int lane = tid & 63, wave = tid >> 6;                                   \
    if (tid < 64) {                                                               \
        W1l[tid] = make_float4(W1[tid * 3], W1[tid * 3 + 1], W1[tid * 3 + 2], b1[tid]); \
        st1[tid] = make_float2(s1t1[tid], s1t1[64 + tid]);                        \
    }                                                                             \
    __syncthreads();                                                              \
    const int i0 = (tid >> 4) * 4, j0 = (tid & 15) * 4;                           \
    float g[4][4];                                                                \
    _Pragma("unroll")                                                             \
    for (int a = 0; a < 4; ++a)                                                   \
        _Pragma("unroll")                                                         \
        for (int c = 0; c < 4; ++c) g[a][c] = 0.f;                                \
    float4 sa4[4];                                                                \
    _Pragma("unroll")                                                             \
    for (int i = 0; i < 4; ++i) sa4[i] = make_float4(0.f, 0.f, 0.f, 0.f);         \
    _Pragma("unroll 1")                                                           \
    for (int ch = 0; ch < NCHUNK; ++ch) {                                         \
        const int s = (blockIdx.x * NCHUNK + ch) * 64 + lane;                     \
        float r0 = rel[s * 3], r1 = rel[s * 3 + 1], r2 = rel[s * 3 + 2];          \
        _Pragma("unroll")                                                         \
        for (int i = 0; i < 4; ++i) {                                             \
            const int c0 = wave * 16 + i * 4;                                     \
            float4 av;                                                            \
            { float4 w = W1l[c0];     float2 st = st1[c0];                        \
              av.x = fmaxf(fmaf(st.x, (w.x*r0 + w.y*r1 + w.z*r2) + w.w, st.y), 0.f); } \
            { float4 w = W1l[c0 + 1]; float2 st = st1[c0 + 1];                    \
              av.y = fmaxf(fmaf(st.x, (w.x*r0 + w.y*r1 + w.z*r2) + w.w, st.y), 0.f); } \
            { float4 w = W1l[c0 + 2]; float2 st = st1[c0 + 2];                    \
              av.z = fmaxf(fmaf(st.x, (w.x*r0 + w.y*r1 + w.z*r2) + w.w, st.y), 0.f); } \
            { float4 w = W1l[c0 + 3]; float2 st = st1[c0 + 3];                    \
              av.w = fmaxf(fmaf(st.x, (w.x*r0 + w.y*r1 + w.z*r2) + w.w, st.y), 0.f); } \
            *(float4*)&A[lane][c0] = av;                                          \
            sa4[i].x += av.x; sa4[i].y += av.y; sa4[i].z += av.z; sa4[i].w += av.w; \
        }                                                                         \
        __syncthreads();                                                          \
        _Pragma("unroll 4")                                                       \
        for (int sl = 0; sl < 64; ++sl) {                                         \
            float4 ai = *(const float4*)&A[sl][i0];                               \
            float4 aj = *(const float4*)&A[sl][j0];                               \
            g[0][0] = fmaf(ai.x, aj.x, g[0][0]); g[0][1] = fmaf(ai.x, aj.y, g[0][1]); \
            g[0][2] = fmaf(ai.x, aj.z, g[0][2]); g[0][3] = fmaf(ai.x, aj.w, g[0][3]); \
            g[1][0] = fmaf(ai.y, aj.x, g[1][0]); g[1][1] = fmaf(ai.y, aj.y, g[1][1]); \
            g[1][2] = fmaf(ai.y, aj.z, g[1][2]); g[1][3] = fmaf(ai.y, aj.w, g[1][3]); \
            g[2][0] = fmaf(ai.z, aj.x, g[2][0]); g[2][1] = fmaf(ai.z, aj.y, g[2][1]); \
            g[2][2] = fmaf(ai.z, aj.z, g[2][2]); g[2][3] = fmaf(ai.z, aj.w, g[2][3]); \
            g[3][0] = fmaf(ai.w, aj.x, g[3][0]); g[3][1] = fmaf(ai.w, aj.y, g[3][1]); \
            g[3][2] = fmaf(ai.w, aj.z, g[3][2]); g[3][3] = fmaf(ai.w, aj.w, g[3][3]); \
        }                                                                         \
        __syncthreads();                                                          \
    }                                                                             \
    _Pragma("unroll")                                                             \
    for (int i = 0; i < 4; ++i) {                                                 \
        float4 v = sa4[i];                                                        \
        _Pragma("unroll")                                                         \
        for (int d = 1; d < 64; d <<= 1) {                                        \
            v.x += __shfl_xor(v.x, d, 64); v.y += __shfl_xor(v.y, d, 64);         \
            v.z += __shfl_xor(v.z, d, 64); v.w += __shfl_xor(v.w, d, 64);         \
        }                                                                         \
        sa4[i] = v;                                                               \
    }

// ---------------- K3a (BIG): per-block partials, no atomics ----------------
__global__ __launch_bounds__(256) void gram_part_kernel(const float* __restrict__ rel,
        const float* __restrict__ W1, const float* __restrict__ b1,
        const float* __restrict__ s1t1,
        float* __restrict__ Gpart, float* __restrict__ sapart) {
    GRAM_BODY(8)
    float* Gp = Gpart + (size_t)blockIdx.x * 4096;
#pragma unroll
    for (int a = 0; a < 4; ++a)
        *(float4*)&Gp[(i0 + a) * 64 + j0] = make_float4(g[a][0], g[a][1], g[a][2], g[a][3]);
    if (lane == 0) {
        float* sp = sapart + (size_t)blockIdx.x * 64 + wave * 16;
#pragma unroll
        for (int i = 0; i < 4; ++i) *(float4*)&sp[i * 4] = sa4[i];
    }
}

// ---------------- K3a2 (BIG): parallel 512->1 reduction, in-place into row 511 --------
// grid 65 x 256: block owns 64 entries; 4 threads/entry, each sums 128 partials (f64,
// fixed order -> deterministic). Each block writes ONLY its own entry-columns of row
// 511; other blocks never read those columns -> race-free without extra memory.
__global__ __launch_bounds__(256) void gred_kernel(float* __restrict__ Gpart,
                                                   float* __restrict__ sapart) {
    __shared__ double red[4][64];
    const int tid = threadIdx.x;
    const int sub = tid & 63;
    const int j   = tid >> 6;                 // p-chunk 0..3
    const int e   = blockIdx.x * 64 + sub;    // 0..4159
    double acc = 0.0;
    if (e < 4096) {
        const float* src = Gpart + e;
        for (int p = j * 128; p < (j + 1) * 128; ++p)
            acc += (double)src[(size_t)p * 4096];
    } else if (e < 4160) {
        const float* src = sapart + (e - 4096);
        for (int p = j * 128; p < (j + 1) * 128; ++p)
            acc += (double)src[(size_t)p * 64];
    }
    red[j][sub] = acc;
    __syncthreads();
    if (j == 0) {
        double t = ((red[0][sub] + red[1][sub]) + red[2][sub]) + red[3][sub];
        if (e < 4096)      Gpart[(size_t)511 * 4096 + e] = (float)t;
        else if (e < 4160) sapart[(size_t)511 * 64 + (e - 4096)] = (float)t;
    }
}

// ---------------- K3b (SMALL fallback, proven R8): fixed-point atomics ------------
__global__ __launch_bounds__(256) void gram_atomic_kernel(const float* __restrict__ rel,
        const float* __restrict__ W1, const float* __restrict__ b1,
        const float* __restrict__ s1t1, unsigned long long* __restrict__ Gfix) {
    GRAM_BODY(16)
#pragma unroll
    for (int a = 0; a < 4; ++a)
#pragma unroll
        for (int c = 0; c < 4; ++c)
            atomicAdd(&Gfix[(i0 + a) * 64 + (j0 + c)],
                      (unsigned long long)((double)g[a][c] * FIXSCALE));
    if (lane == 0) {
#pragma unroll
        for (int i = 0; i < 4; ++i) {
            const int c0 = wave * 16 + i * 4;
            atomicAdd(&Gfix[4096 + c0 + 0], (unsigned long long)((double)sa4[i].x * FIXSCALE));
            atomicAdd(&Gfix[4096 + c0 + 1], (unsigned long long)((double)sa4[i].y * FIXSCALE));
            atomicAdd(&Gfix[4096 + c0 + 2], (unsigned long long)((double)sa4[i].z * FIXSCALE));
            atomicAdd(&Gfix[4096 + c0 + 3], (unsigned long long)((double)sa4[i].w * FIXSCALE));
        }
    }
}

// ======== shared fin2G tail (R11-verbatim) ========
#define FIN2G_TAIL                                                                \
    const int o = tid & 63, part = tid >> 6;                                      \
    float partial = 0.f;                                                          \
    _Pragma("unroll")                                                             \
    for (int ii = 0; ii < 4; ++ii) {                                              \
        const int i = part * 4 + ii;                                              \
        float t2 = 0.f;                                                           \
        _Pragma("unroll")                                                         \
        for (int j = 0; j < 64; j += 4) {                                         \
            float4 wj = *(const float4*)&w2s[o][j];                               \
            float4 gj = *(const float4*)&Gs[i][j];                                \
            t2 = fmaf(wj.x, gj.x, t2); t2 = fmaf(wj.y, gj.y, t2);                 \
            t2 = fmaf(wj.z, gj.z, t2); t2 = fmaf(wj.w, gj.w, t2);                 \
        }                                                                         \
        partial = fmaf(w2s[o][i], t2, partial);                                   \
    }                                                                             \
    red[part][o] = partial;                                                       \
    __syncthreads();                                                              \
    if (tid < 64) {                                                               \
        double qf = 0.0;                                                          \
        _Pragma("unroll")                                                         \
        for (int p = 0; p < 16; ++p) qf += (double)red[p][tid];                   \
        double SA = 0.0;                                                          \
        for (int c = 0; c < 64; ++c) SA += (double)w2s[tid][c] * (double)sa_s[c]; \
        const double Md = (double)M_SAMPLES;                                      \
        double mean = SA / Md + (double)b2[tid];                                  \
        double var  = qf / Md - (SA / Md) * (SA / Md);                            \
        double sc = (double)gamma[tid] / sqrt(var + 1e-5);                        \
        s2t2[tid]      = (float)sc;                                               \
        s2t2[64 + tid] = (float)((double)beta[tid] - mean * sc);                  \
    }

// ---------------- K4a (BIG): finalize from reduced row 511 ----------------
__global__ __launch_bounds__(1024) void fin2G_part_kernel(const float* __restrict__ Gpart,
                            const float* __restrict__ sapart,
                            const float* __restrict__ W2, const float* __restrict__ b2,
                            const float* __restrict__ gamma, const float* __restrict__ beta,
                            float* __restrict__ s2t2) {
    __shared__ float Gs[64][68];
    __shared__ float w2s[64][68];
    __shared__ float sa_s[64];
    __shared__ float red[16][64];
    const int tid = threadIdx.x;
    for (int i = tid; i < 4096; i += 1024) {
        Gs[i >> 6][i & 63]  = Gpart[(size_t)511 * 4096 + i];
        w2s[i >> 6][i & 63] = W2[i];
    }
    if (tid < 64) sa_s[tid] = sapart[(size_t)511 * 64 + tid];
    __syncthreads();
    FIN2G_TAIL
}

// ---------------- K4b (SMALL fallback, proven R8) ----------------
__global__ __launch_bounds__(1024) void fin2G_atomic_kernel(const unsigned long long* __restrict__ Gfix,
                            const float* __restrict__ W2, const float* __restrict__ b2,
                            const float* __restrict__ gamma, const float* __restrict__ beta,
                            float* __restrict__ s2t2) {
    __shared__ float Gs[64][68];
    __shared__ float w2s[64][68];
    __shared__ float sa_s[64];
    __shared__ float red[16][64];
    const int tid = threadIdx.x;
    const double INV = 1.0 / FIXSCALE;
    for (int i = tid; i < 4096; i += 1024) {
        Gs[i >> 6][i & 63]  = (float)((double)Gfix[i] * INV);
        w2s[i >> 6][i & 63] = W2[i];
    }
    if (tid < 64) sa_s[tid] = (float)((double)Gfix[4096 + tid] * INV);
    __syncthreads();
    FIN2G_TAIL
}

// ---------------- K5: block-GEMM chain + max over k (R9-verbatim, proven) --------------
#define FMA4(cv, s, wv) { cv.x = fmaf(s, wv.x, cv.x); cv.y = fmaf(s, wv.y, cv.y); \
                          cv.z = fmaf(s, wv.z, cv.z); cv.w = fmaf(s, wv.w, cv.w); }
__global__ __launch_bounds__(256) void out_kernel(const float* __restrict__ rel,
        const float* __restrict__ W1, const float* __restrict__ b1,
        const float* __restrict__ W2, const float* __restrict__ b2,
        const float* __restrict__ s1t1, const float* __restrict__ s2t2,
        float* __restrict__ out) {
    __shared__ float  W2T[64][68];
    __shared__ float  A[64][68];
    __shared__ float4 W1l[64];
    __shared__ float2 st1[64];
    __shared__ float2 st2[64];
    __shared__ float  b2l[64];
    __shared__ float  Mred[1024];

    const int tid = threadIdx.x;
    const int lane = tid & 63, wave = tid >> 6;
    const int sbase = blockIdx.x * 64;

    for (int i = tid; i < 4096; i += 256) W2T[i & 63][i >> 6] = W2[i];
    if (tid < 64) {
        W1l[tid] = make_float4(W1[tid * 3], W1[tid * 3 + 1], W1[tid * 3 + 2], b1[tid]);
        st1[tid] = make_float2(s1t1[tid], s1t1[64 + tid]);
        st2[tid] = make_float2(s2t2[tid], s2t2[64 + tid]);
        b2l[tid] = b2[tid];
    }
    const int s = sbase + lane;
    float r0 = rel[s * 3], r1 = rel[s * 3 + 1], r2 = rel[s * 3 + 2];
    __syncthreads();

#pragma unroll
    for (int i = 0; i < 4; ++i) {
        const int c0 = wave * 16 + i * 4;
        float4 av;
        {
            float4 w = W1l[c0];     float2 st = st1[c0];
            av.x = fmaxf(fmaf(st.x, (w.x * r0 + w.y * r1 + w.z * r2) + w.w, st.y), 0.f);
        }
        {
            float4 w = W1l[c0 + 1]; float2 st = st1[c0 + 1];
            av.y = fmaxf(fmaf(st.x, (w.x * r0 + w.y * r1 + w.z * r2) + w.w, st.y), 0.f);
        }
        {
            float4 w = W1l[c0 + 2]; float2 st = st1[c0 + 2];
            av.z = fmaxf(fmaf(st.x, (w.x * r0 + w.y * r1 + w.z * r2) + w.w, st.y), 0.f);
        }
        {
            float4 w = W1l[c0 + 3]; float2 st = st1[c0 + 3];
            av.w = fmaxf(fmaf(st.x, (w.x * r0 + w.y * r1 + w.z * r2) + w.w, st.y), 0.f);
        }
        *(float4*)&A[lane][c0] = av;
    }
    __syncthreads();

    const int i0 = (tid >> 4) * 4;
    const int j0 = (tid & 15) * 4;
    const float4 bj = make_float4(b2l[j0], b2l[j0 + 1], b2l[j0 + 2], b2l[j0 + 3]);

    float4 c0v = {0, 0, 0, 0}, c1v = {0, 0, 0, 0}, c2v = {0, 0, 0, 0}, c3v = {0, 0, 0, 0};
#pragma unroll
    for (int k4 = 0; k4 < 16; ++k4) {
        const int k = k4 * 4;
        float4 a0 = *(const float4*)&A[i0 + 0][k];
        float4 a1 = *(const float4*)&A[i0 + 1][k];
        float4 a2 = *(const float4*)&A[i0 + 2][k];
        float4 a3 = *(const float4*)&A[i0 + 3][k];
        float4 w0 = *(const float4*)&W2T[k + 0][j0];
        float4 w1 = *(const float4*)&W2T[k + 1][j0];
        float4 w2 = *(const float4*)&W2T[k + 2][j0];
        float4 w3 = *(const float4*)&W2T[k + 3][j0];
        FMA4(c0v, a0.x, w0) FMA4(c0v, a0.y, w1) FMA4(c0v, a0.z, w2) FMA4(c0v, a0.w, w3)
        FMA4(c1v, a1.x, w0) FMA4(c1v, a1.y, w1) FMA4(c1v, a1.z, w2) FMA4(c1v, a1.w, w3)
        FMA4(c2v, a2.x, w0) FMA4(c2v, a2.y, w1) FMA4(c2v, a2.z, w2) FMA4(c2v, a2.w, w3)
        FMA4(c3v, a3.x, w0) FMA4(c3v, a3.y, w1) FMA4(c3v, a3.z, w2) FMA4(c3v, a3.w, w3)
    }
    const float2 sA = st2[j0], sB = st2[j0 + 1], sC = st2[j0 + 2], sD = st2[j0 + 3];
#define EPI1(cv) { cv.x = fmaxf(fmaf(sA.x, cv.x + bj.x, sA.y), 0.f); \
                   cv.y = fmaxf(fmaf(sB.x, cv.y + bj.y, sB.y), 0.f); \
                   cv.z = fmaxf(fmaf(sC.x, cv.z + bj.z, sC.y), 0.f); \
                   cv.w = fmaxf(fmaf(sD.x, cv.w + bj.w, sD.y), 0.f); }
    EPI1(c0v) EPI1(c1v) EPI1(c2v) EPI1(c3v)
    __syncthreads();
    *(float4*)&A[i0 + 0][j0] = c0v;
    *(float4*)&A[i0 + 1][j0] = c1v;
    *(float4*)&A[i0 + 2][j0] = c2v;
    *(float4*)&A[i0 + 3][j0] = c3v;
    __syncthreads();

    float4 d0v = {0, 0, 0, 0}, d1v = {0, 0, 0, 0}, d2v = {0, 0, 0, 0}, d3v = {0, 0, 0, 0};
#pragma unroll
    for (int k4 = 0; k4 < 16; ++k4) {
        const int k = k4 * 4;
        float4 a0 = *(const float4*)&A[i0 + 0][k];
        float4 a1 = *(const float4*)&A[i0 + 1][k];
        float4 a2 = *(const float4*)&A[i0 + 2][k];
        float4 a3 = *(const float4*)&A[i0 + 3][k];
        float4 w0 = *(const float4*)&W2T[k + 0][j0];
        float4 w1 = *(const float4*)&W2T[k + 1][j0];
        float4 w2 = *(const float4*)&W2T[k + 2][j0];
        float4 w3 = *(const float4*)&W2T[k + 3][j0];
        FMA4(d0v, a0.x, w0) FMA4(d0v, a0.y, w1) FMA4(d0v, a0.z, w2) FMA4(d0v, a0.w, w3)
        FMA4(d1v, a1.x, w0) FMA4(d1v, a1.y, w1) FMA4(d1v, a1.z, w2) FMA4(d1v, a1.w, w3)
        FMA4(d2v, a2.x, w0) FMA4(d2v, a2.y, w1) FMA4(d2v, a2.z, w2) FMA4(d2v, a2.w, w3)
        FMA4(d3v, a3.x, w0) FMA4(d3v, a3.y, w1) FMA4(d3v, a3.z, w2) FMA4(d3v, a3.w, w3)
    }
    float4 pm;
    pm.x = fmaxf(fmaxf(d0v.x, d1v.x), fmaxf(d2v.x, d3v.x)) + bj.x;
    pm.y = fmaxf(fmaxf(d0v.y, d1v.y), fmaxf(d2v.y, d3v.y)) + bj.y;
    pm.z = fmaxf(fmaxf(d0v.z, d1v.z), fmaxf(d2v.z, d3v.z)) + bj.z;
    pm.w = fmaxf(fmaxf(d0v.w, d1v.w), fmaxf(d2v.w, d3v.w)) + bj.w;
    const int nl = i0 >> 4, dd = (i0 >> 2) & 3, jj = tid & 15;
    *(float4*)&Mred[((nl * 4 + dd) * 16 + jj) * 4] = pm;
    __syncthreads();

    {
        const int n = tid >> 6, o = tid & 63;
        float m = Mred[n * 256 + 0 * 64 + o];
        m = fmaxf(m, Mred[n * 256 + 1 * 64 + o]);
        m = fmaxf(m, Mred[n * 256 + 2 * 64 + o]);
        m = fmaxf(m, Mred[n * 256 + 3 * 64 + o]);
        const int sg = sbase + n * 16;
        const int bb = sg >> 15;
        const int nn = (sg >> 4) & (NPTS - 1);
        out[(size_t)bb * (CH * NPTS) + o * NPTS + nn] = m;
    }
}

extern "C" void kernel_launch(void* const* d_in, const int* in_sizes, int n_in,
                              void* d_out, int out_size, void* d_ws, size_t ws_size,
                              hipStream_t stream) {
    (void)in_sizes; (void)n_in; (void)out_size;
    const float* xyz   = (const float*)d_in[0];
    const float* W1    = (const float*)d_in[1];
    const float* b1    = (const float*)d_in[2];
    const float* W2    = (const float*)d_in[3];
    const float* b2    = (const float*)d_in[4];
    const float* gamma = (const float*)d_in[5];
    const float* beta  = (const float*)d_in[6];
    float* out = (float*)d_out;
    float* ws  = (float*)d_ws;

    float* rel    = ws + WS_REL;
    float* s1t1   = ws + WS_S1T1;
    float* s2t2   = ws + WS_S2T2;
    float* part1  = ws + WS_PART1;
    float* Gpart  = ws + WS_GPART;
    float* sapart = ws + WS_SAPART;
    unsigned long long* Gfix = (unsigned long long*)(ws + WS_GFIX);

    const bool big = ws_size >= WS_BIG_FLOATS * 4ull;   // constant -> capture-safe

    knn_rel_kernel<<<dim3(4096), dim3(256), 0, stream>>>(xyz, rel, part1);
    fin1_kernel<<<dim3(1), dim3(256), 0, stream>>>(part1, W1, b1, gamma, beta, s1t1, Gfix);
    if (big) {
        gram_part_kernel<<<dim3(GPART_BLKS), dim3(256), 0, stream>>>(rel, W1, b1, s1t1, Gpart, sapart);
        gred_kernel<<<dim3(65), dim3(256), 0, stream>>>(Gpart, sapart);
        fin2G_part_kernel<<<dim3(1), dim3(1024), 0, stream>>>(Gpart, sapart, W2, b2, gamma, beta, s2t2);
    } else {
        gram_atomic_kernel<<<dim3(256), dim3(256), 0, stream>>>(rel, W1, b1, s1t1, Gfix);
        fin2G_atomic_kernel<<<dim3(1), dim3(1024), 0, stream>>>(Gfix, W2, b2, gamma, beta, s2t2);
    }
    out_kernel<<<dim3(4096), dim3(256), 0, stream>>>(rel, W1, b1, W2, b2, s1t1, s2t2, out);
}

// Round 13
// 138.835 us; speedup vs baseline: 2.2414x; 1.2160x over previous
//
#include <hip/hip_runtime.h>
#include <math.h>

#define BATCH 8
#define NPTS 2048
#define CH 64
#define KNB 16
#define M_SAMPLES (BATCH * NPTS * KNB)   // 262144
#define FIXSCALE 1048576.0               // 2^20 fixed-point (atomic fallback path)
#define GPART_BLKS 512

// ws layout (float offsets) — IDENTICAL to R12:
//   rel    : [0, 786432)         262144 * 3 f32
//   s1t1   : [786432, 786560)
//   s2t2   : [786560, 786688)
//   part1  : [786688, 823552)    4096*9 (knn -> fin1; dead after fin1)
//   BIG path (ws >= 11.67 MB):
//     Gpart : [786688, 2883840)  512 blocks * 4096 f32 (aliases part1)
//     sapart: [2883840, 2916608) 512 * 64 f32
//   SMALL path (fallback, proven R8):
//     Gfix  : [786688, 795008)   4160 u64
#define WS_REL    0
#define WS_S1T1   786432
#define WS_S2T2   786560
#define WS_PART1  786688
#define WS_GFIX   786688
#define WS_GPART  786688
#define WS_SAPART 2883840
#define WS_BIG_FLOATS 2916608ull

#define SURV_CAP 192
#define D2_EPS 1e-4f

typedef __attribute__((ext_vector_type(8))) short short8;
typedef __attribute__((ext_vector_type(4))) float f32x4;

__device__ __forceinline__ unsigned long long u64min(unsigned long long a, unsigned long long b) { return a < b ? a : b; }
__device__ __forceinline__ unsigned long long u64max(unsigned long long a, unsigned long long b) { return a > b ? a : b; }

__device__ __forceinline__ unsigned long long bitonic64(unsigned long long v, int lane) {
#pragma unroll
    for (int k = 2; k <= 64; k <<= 1)
#pragma unroll
        for (int d = k >> 1; d >= 1; d >>= 1) {
            unsigned long long o = __shfl_xor(v, d, 64);
            bool keepmin = (((lane & d) == 0) == ((lane & k) == 0));
            v = keepmin ? u64min(v, o) : u64max(v, o);
        }
    return v;
}

__device__ __forceinline__ unsigned long long cand_key(const float4 pq, const float4 pj, int j, int q) {
    float dot = pq.x * pj.x + pq.y * pj.y + pq.z * pj.z;
    float d2 = fmaxf((pq.w + pj.w) - 2.0f * dot, 0.0f);
    unsigned long long key = ((unsigned long long)__float_as_uint(d2) << 32) | (unsigned int)j;
    return (j == q) ? ~0ull : key;
}

// bf16 round-to-nearest-even
__device__ __forceinline__ unsigned int bf16r(float x) {
    unsigned int u = __float_as_uint(x);
    return (u + 0x7FFFu + ((u >> 16) & 1u)) >> 16;
}
// byte offset into a [64][64]-bf16 LDS tile, XOR-swizzled (G4: (row&7)<<4)
__device__ __forceinline__ int swz(int row, int kbyte) {
    return (row << 7) + (kbyte ^ ((row & 7) << 4));
}

// ---------------- K1: KNN (R7-verbatim, proven) ----------------
__global__ __launch_bounds__(256) void knn_rel_kernel(const float* __restrict__ xyz,
                                                      float* __restrict__ rel,
                                                      float* __restrict__ part1) {
    __shared__ float4 pts[NPTS];
    __shared__ unsigned long long surv[4][SURV_CAP];
    __shared__ unsigned int wavecnt[4];
    __shared__ float red9[4][9];

    const int b     = blockIdx.x >> 9;
    const int qbase = (blockIdx.x & 511) * 4;
    const int tid   = threadIdx.x;
    const int wave  = tid >> 6, lane = tid & 63;

    const float* xb = xyz + (size_t)b * 3 * NPTS;
    for (int j = tid; j < NPTS; j += 256) {
        float x = xb[j], y = xb[NPTS + j], z = xb[2 * NPTS + j];
        pts[j] = make_float4(x, y, z, (x * x + y * y) + z * z);
    }
    __syncthreads();

    const int q = qbase + wave;
    const float4 pq = pts[q];

    unsigned long long lm = ~0ull;
#pragma unroll
    for (int t = 0; t < 32; ++t) {
        const int j = t * 64 + lane;
        lm = u64min(lm, cand_key(pq, pts[j], j, q));
    }
    unsigned long long sorted = bitonic64(lm, lane);
    const float Td2 = __uint_as_float((unsigned int)(__shfl(sorted, 15, 64) >> 32)) + D2_EPS;

    if (lane == 0) wavecnt[wave] = 0u;
#pragma unroll
    for (int t = 0; t < 32; ++t) {
        const int j = t * 64 + lane;
        unsigned long long key = cand_key(pq, pts[j], j, q);
        float d2 = __uint_as_float((unsigned int)(key >> 32));
        if (d2 <= Td2) {
            unsigned int pos = atomicAdd(&wavecnt[wave], 1u);
            if (pos < SURV_CAP) surv[wave][pos] = key;
        }
    }
    const unsigned int total = wavecnt[wave];

    unsigned long long wkey = ~0ull;
    bool ok = false;
    if (total >= 16u && total <= 64u) {
        unsigned long long s0 = (lane < (int)total) ? surv[wave][lane] : ~0ull;
        wkey = bitonic64(s0, lane);
        unsigned long long nxt = __shfl_down(wkey, 1, 64);
        ok = __all((lane == 63) || (wkey <= nxt)) != 0;
    }
    if (!ok) {
        unsigned long long last = 0ull; bool first = true;
#pragma unroll 1
        for (int r = 0; r < 16; ++r) {
            unsigned long long m = ~0ull;
#pragma unroll
            for (int t = 0; t < 32; ++t) {
                const int j = t * 64 + lane;
                unsigned long long key = cand_key(pq, pts[j], j, q);
                if (first || key > last) m = u64min(m, key);
            }
#pragma unroll
            for (int d = 1; d < 64; d <<= 1) m = u64min(m, __shfl_xor(m, d, 64));
            if (lane == r) wkey = m;
            last = m; first = false;
        }
    }

    float rr0 = 0.f, rr1 = 0.f, rr2 = 0.f;
    if (lane < 16) {
        const int j = ((int)(unsigned int)wkey) & (NPTS - 1);
        float4 pn = pts[j];
        rr0 = pn.x - pq.x; rr1 = pn.y - pq.y; rr2 = pn.z - pq.z;
        const size_t relbase = ((size_t)(b * NPTS + q)) * (KNB * 3);
        rel[relbase + lane * 3 + 0] = rr0;
        rel[relbase + lane * 3 + 1] = rr1;
        rel[relbase + lane * 3 + 2] = rr2;
    }
    float m0 = rr0, m1 = rr1, m2 = rr2;
    float m3 = rr0 * rr0, m4 = rr0 * rr1, m5 = rr0 * rr2;
    float m6 = rr1 * rr1, m7 = rr1 * rr2, m8 = rr2 * rr2;
#pragma unroll
    for (int d = 1; d < 64; d <<= 1) {
        m0 += __shfl_xor(m0, d, 64); m1 += __shfl_xor(m1, d, 64); m2 += __shfl_xor(m2, d, 64);
        m3 += __shfl_xor(m3, d, 64); m4 += __shfl_xor(m4, d, 64); m5 += __shfl_xor(m5, d, 64);
        m6 += __shfl_xor(m6, d, 64); m7 += __shfl_xor(m7, d, 64); m8 += __shfl_xor(m8, d, 64);
    }
    if (lane == 0) {
        red9[wave][0] = m0; red9[wave][1] = m1; red9[wave][2] = m2;
        red9[wave][3] = m3; red9[wave][4] = m4; red9[wave][5] = m5;
        red9[wave][6] = m6; red9[wave][7] = m7; red9[wave][8] = m8;
    }
    __syncthreads();
    if (tid < 9)
        part1[blockIdx.x * 9 + tid] =
            red9[0][tid] + red9[1][tid] + red9[2][tid] + red9[3][tid];
}

// ---------------- K2: finalize BN1 affine (R12-verbatim) ----------
__global__ __launch_bounds__(256) void fin1_kernel(const float* __restrict__ part1,
                            const float* __restrict__ W1, const float* __restrict__ b1,
                            const float* __restrict__ gamma, const float* __restrict__ beta,
                            float* __restrict__ s1t1, unsigned long long* __restrict__ Gfix) {
    __shared__ double red[9][256];
    __shared__ double sm[9];
    const int t = threadIdx.x;
    double s[9] = {0, 0, 0, 0, 0, 0, 0, 0, 0};
    for (int blk = t; blk < 4096; blk += 256)
#pragma unroll
        for (int v = 0; v < 9; ++v) s[v] += (double)part1[blk * 9 + v];
#pragma unroll
    for (int v = 0; v < 9; ++v) red[v][t] = s[v];
    __syncthreads();
    for (int i = t; i < 4160; i += 256) Gfix[i] = 0ull;
    if (t < 9) {
        double x = 0.0;
        for (int i = 0; i < 256; ++i) x += red[t][i];
        sm[t] = x;
    }
    __syncthreads();
    if (t < 64) {
        const double Md = (double)M_SAMPLES;
        double mu0 = sm[0] / Md, mu1 = sm[1] / Md, mu2 = sm[2] / Md;
        double C00 = sm[3] / Md - mu0 * mu0;
        double C01 = sm[4] / Md - mu0 * mu1;
        double C02 = sm[5] / Md - mu0 * mu2;
        double C11 = sm[6] / Md - mu1 * mu1;
        double C12 = sm[7] / Md - mu1 * mu2;
        double C22 = sm[8] / Md - mu2 * mu2;
        double w0 = (double)W1[t * 3], w1 = (double)W1[t * 3 + 1], w2 = (double)W1[t * 3 + 2];
        double mean = w0 * mu0 + w1 * mu1 + w2 * mu2 + (double)b1[t];
        double var  = w0 * w0 * C00 + w1 * w1 * C11 + w2 * w2 * C22
                    + 2.0 * (w0 * w1 * C01 + w0 * w2 * C02 + w1 * w2 * C12);
        double sc = (double)gamma[t] / sqrt(var + 1e-5);
        s1t1[t]      = (float)sc;
        s1t1[64 + t] = (float)((double)beta[t] - mean * sc);
    }
}

// ======== shared gram body (R12-verbatim) ========
#define GRAM_BODY(NCHUNK)                                                         \
    __shared__ float  A[64][68];                                                  \
    __shared__ float4 W1l[64];                                                    \
    __shared__ float2 st1[64];                                                    \
    const int tid = threadIdx.x;                                                  \
    const int lane = tid & 63, wave = tid >> 6;                                   \
    if (tid < 64) {                                                               \
        W1l[tid] = make_float4(W1[tid * 3], W1[tid * 3 + 1], W1[tid * 3 + 2], b1[tid]); \
        st1[tid] = make_float2(s1t1[tid], s1t1[64 + tid]);                        \
    }                                                                             \
    __syncthreads();                                                              \
    const int i0 = (tid >> 4) * 4, j0 = (tid & 15) * 4;                           \
    float g[4][4];                                                                \
    _Pragma("unroll")                                                             \
    for (int a = 0; a < 4; ++a)                                                   \
        _Pragma("unroll")                                                         \
        for (int c = 0; c < 4; ++c) g[a][c] = 0.f;                                \
    float4 sa4[4];                                                                \
    _Pragma("unroll")                                                             \
    for (int i = 0; i < 4; ++i) sa4[i] = make_float4(0.f, 0.f, 0.f, 0.f);         \
    _Pragma("unroll 1")                                                           \
    for (int ch = 0; ch < NCHUNK; ++ch) {                                         \
        const int s = (blockIdx.x * NCHUNK + ch) * 64 + lane;                     \
        float r0 = rel[s * 3], r1 = rel[s * 3 + 1], r2 = rel[s * 3 + 2];          \
        _Pragma("unroll")                                                         \
        for (int i = 0; i < 4; ++i) {                                             \
            const int c0 = wave * 16 + i * 4;                                     \
            float4 av;                                                            \
            { float4 w = W1l[c0];     float2 st = st1[c0];                        \
              av.x = fmaxf(fmaf(st.x, (w.x*r0 + w.y*r1 + w.z*r2) + w.w, st.y), 0.f); } \
            { float4 w = W1l[c0 + 1]; float2 st = st1[c0 + 1];                    \
              av.y = fmaxf(fmaf(st.x, (w.x*r0 + w.y*r1 + w.z*r2) + w.w, st.y), 0.f); } \
            { float4 w = W1l[c0 + 2]; float2 st = st1[c0 + 2];                    \
              av.z = fmaxf(fmaf(st.x, (w.x*r0 + w.y*r1 + w.z*r2) + w.w, st.y), 0.f); } \
            { float4 w = W1l[c0 + 3]; float2 st = st1[c0 + 3];                    \
              av.w = fmaxf(fmaf(st.x, (w.x*r0 + w.y*r1 + w.z*r2) + w.w, st.y), 0.f); } \
            *(float4*)&A[lane][c0] = av;                                          \
            sa4[i].x += av.x; sa4[i].y += av.y; sa4[i].z += av.z; sa4[i].w += av.w; \
        }                                                                         \
        __syncthreads();                                                          \
        _Pragma("unroll 4")                                                       \
        for (int sl = 0; sl < 64; ++sl) {                                         \
            float4 ai = *(const float4*)&A[sl][i0];                               \
            float4 aj = *(const float4*)&A[sl][j0];                               \
            g[0][0] = fmaf(ai.x, aj.x, g[0][0]); g[0][1] = fmaf(ai.x, aj.y, g[0][1]); \
            g[0][2] = fmaf(ai.x, aj.z, g[0][2]); g[0][3] = fmaf(ai.x, aj.w, g[0][3]); \
            g[1][0] = fmaf(ai.y, aj.x, g[1][0]); g[1][1] = fmaf(ai.y, aj.y, g[1][1]); \
            g[1][2] = fmaf(ai.y, aj.z, g[1][2]); g[1][3] = fmaf(ai.y, aj.w, g[1][3]); \
            g[2][0] = fmaf(ai.z, aj.x, g[2][0]); g[2][1] = fmaf(ai.z, aj.y, g[2][1]); \
            g[2][2] = fmaf(ai.z, aj.z, g[2][2]); g[2][3] = fmaf(ai.z, aj.w, g[2][3]); \
            g[3][0] = fmaf(ai.w, aj.x, g[3][0]); g[3][1] = fmaf(ai.w, aj.y, g[3][1]); \
            g[3][2] = fmaf(ai.w, aj.z, g[3][2]); g[3][3] = fmaf(ai.w, aj.w, g[3][3]); \
        }                                                                         \
        __syncthreads();                                                          \
    }                                                                             \
    _Pragma("unroll")                                                             \
    for (int i = 0; i < 4; ++i) {                                                 \
        float4 v = sa4[i];                                                        \
        _Pragma("unroll")                                                         \
        for (int d = 1; d < 64; d <<= 1) {                                        \
            v.x += __shfl_xor(v.x, d, 64); v.y += __shfl_xor(v.y, d, 64);         \
            v.z += __shfl_xor(v.z, d, 64); v.w += __shfl_xor(v.w, d, 64);         \
        }                                                                         \
        sa4[i] = v;                                                               \
    }

// ---------------- K3a (BIG): per-block partials (R12-verbatim) ----------------
__global__ __launch_bounds__(256) void gram_part_kernel(const float* __restrict__ rel,
        const float* __restrict__ W1, const float* __restrict__ b1,
        const float* __restrict__ s1t1,
        float* __restrict__ Gpart, float* __restrict__ sapart) {
    GRAM_BODY(8)
    float* Gp = Gpart + (size_t)blockIdx.x * 4096;
#pragma unroll
    for (int a = 0; a < 4; ++a)
        *(float4*)&Gp[(i0 + a) * 64 + j0] = make_float4(g[a][0], g[a][1], g[a][2], g[a][3]);
    if (lane == 0) {
        float* sp = sapart + (size_t)blockIdx.x * 64 + wave * 16;
#pragma unroll
        for (int i = 0; i < 4; ++i) *(float4*)&sp[i * 4] = sa4[i];
    }
}

// ---------------- K3a2 (BIG): parallel 512->1 reduction (R12-verbatim) --------
__global__ __launch_bounds__(256) void gred_kernel(float* __restrict__ Gpart,
                                                   float* __restrict__ sapart) {
    __shared__ double red[4][64];
    const int tid = threadIdx.x;
    const int sub = tid & 63;
    const int j   = tid >> 6;
    const int e   = blockIdx.x * 64 + sub;
    double acc = 0.0;
    if (e < 4096) {
        const float* src = Gpart + e;
        for (int p = j * 128; p < (j + 1) * 128; ++p)
            acc += (double)src[(size_t)p * 4096];
    } else if (e < 4160) {
        const float* src = sapart + (e - 4096);
        for (int p = j * 128; p < (j + 1) * 128; ++p)
            acc += (double)src[(size_t)p * 64];
    }
    red[j][sub] = acc;
    __syncthreads();
    if (j == 0) {
        double t = ((red[0][sub] + red[1][sub]) + red[2][sub]) + red[3][sub];
        if (e < 4096)      Gpart[(size_t)511 * 4096 + e] = (float)t;
        else if (e < 4160) sapart[(size_t)511 * 64 + (e - 4096)] = (float)t;
    }
}

// ---------------- K3b (SMALL fallback, proven R8) ------------
__global__ __launch_bounds__(256) void gram_atomic_kernel(const float* __restrict__ rel,
        const float* __restrict__ W1, const float* __restrict__ b1,
        const float* __restrict__ s1t1, unsigned long long* __restrict__ Gfix) {
    GRAM_BODY(16)
#pragma unroll
    for (int a = 0; a < 4; ++a)
#pragma unroll
        for (int c = 0; c < 4; ++c)
            atomicAdd(&Gfix[(i0 + a) * 64 + (j0 + c)],
                      (unsigned long long)((double)g[a][c] * FIXSCALE));
    if (lane == 0) {
#pragma unroll
        for (int i = 0; i < 4; ++i) {
            const int c0 = wave * 16 + i * 4;
            atomicAdd(&Gfix[4096 + c0 + 0], (unsigned long long)((double)sa4[i].x * FIXSCALE));
            atomicAdd(&Gfix[4096 + c0 + 1], (unsigned long long)((double)sa4[i].y * FIXSCALE));
            atomicAdd(&Gfix[4096 + c0 + 2], (unsigned long long)((double)sa4[i].z * FIXSCALE));
            atomicAdd(&Gfix[4096 + c0 + 3], (unsigned long long)((double)sa4[i].w * FIXSCALE));
        }
    }
}

// ======== shared fin2G tail (R12-verbatim) ========
#define FIN2G_TAIL                                                                \
    const int o = tid & 63, part = tid >> 6;                                      \
    float partial = 0.f;                                                          \
    _Pragma("unroll")                                                             \
    for (int ii = 0; ii < 4; ++ii) {                                              \
        const int i = part * 4 + ii;                                              \
        float t2 = 0.f;                                                           \
        _Pragma("unroll")                                                         \
        for (int j = 0; j < 64; j += 4) {                                         \
            float4 wj = *(const float4*)&w2s[o][j];                               \
            float4 gj = *(const float4*)&Gs[i][j];                                \
            t2 = fmaf(wj.x, gj.x, t2); t2 = fmaf(wj.y, gj.y, t2);                 \
            t2 = fmaf(wj.z, gj.z, t2); t2 = fmaf(wj.w, gj.w, t2);                 \
        }                                                                         \
        partial = fmaf(w2s[o][i], t2, partial);                                   \
    }                                                                             \
    red[part][o] = partial;                                                       \
    __syncthreads();                                                              \
    if (tid < 64) {                                                               \
        double qf = 0.0;                                                          \
        _Pragma("unroll")                                                         \
        for (int p = 0; p < 16; ++p) qf += (double)red[p][tid];                   \
        double SA = 0.0;                                                          \
        for (int c = 0; c < 64; ++c) SA += (double)w2s[tid][c] * (double)sa_s[c]; \
        const double Md = (double)M_SAMPLES;                                      \
        double mean = SA / Md + (double)b2[tid];                                  \
        double var  = qf / Md - (SA / Md) * (SA / Md);                            \
        double sc = (double)gamma[tid] / sqrt(var + 1e-5);                        \
        s2t2[tid]      = (float)sc;                                               \
        s2t2[64 + tid] = (float)((double)beta[tid] - mean * sc);                  \
    }

// ---------------- K4a (BIG): finalize from reduced row 511 (R12-verbatim) -------------
__global__ __launch_bounds__(1024) void fin2G_part_kernel(const float* __restrict__ Gpart,
                            const float* __restrict__ sapart,
                            const float* __restrict__ W2, const float* __restrict__ b2,
                            const float* __restrict__ gamma, const float* __restrict__ beta,
                            float* __restrict__ s2t2) {
    __shared__ float Gs[64][68];
    __shared__ float w2s[64][68];
    __shared__ float sa_s[64];
    __shared__ float red[16][64];
    const int tid = threadIdx.x;
    for (int i = tid; i < 4096; i += 1024) {
        Gs[i >> 6][i & 63]  = Gpart[(size_t)511 * 4096 + i];
        w2s[i >> 6][i & 63] = W2[i];
    }
    if (tid < 64) sa_s[tid] = sapart[(size_t)511 * 64 + tid];
    __syncthreads();
    FIN2G_TAIL
}

// ---------------- K4b (SMALL fallback, proven R8) ----------------
__global__ __launch_bounds__(1024) void fin2G_atomic_kernel(const unsigned long long* __restrict__ Gfix,
                            const float* __restrict__ W2, const float* __restrict__ b2,
                            const float* __restrict__ gamma, const float* __restrict__ beta,
                            float* __restrict__ s2t2) {
    __shared__ float Gs[64][68];
    __shared__ float w2s[64][68];
    __shared__ float sa_s[64];
    __shared__ float red[16][64];
    const int tid = threadIdx.x;
    const double INV = 1.0 / FIXSCALE;
    for (int i = tid; i < 4096; i += 1024) {
        Gs[i >> 6][i & 63]  = (float)((double)Gfix[i] * INV);
        w2s[i >> 6][i & 63] = W2[i];
    }
    if (tid < 64) sa_s[tid] = (float)((double)Gfix[4096 + tid] * INV);
    __syncthreads();
    FIN2G_TAIL
}

// ---------------- K5: MFMA bf16 block-GEMM chain + max over k ----------------
// grid 4096 (64 samples/block), block 256 = 4 waves, wave-private after staging.
// Both GEMMs computed TRANSPOSED: D^T[o][s] = mfma(A=W2-rows, B=activations).
// C/D layout (m89-verified): col = lane&15, row = (lane>>4)*4 + reg.
__global__ __launch_bounds__(256) void out_kernel(const float* __restrict__ rel,
        const float* __restrict__ W1, const float* __restrict__ b1,
        const float* __restrict__ W2, const float* __restrict__ b2,
        const float* __restrict__ s1t1, const float* __restrict__ s2t2,
        float* __restrict__ out) {
    __shared__ unsigned short Wb[64 * 64];   // W2 bf16 row-major [o][k], swizzled
    __shared__ unsigned short Ab[64 * 64];   // activations bf16 [s_loc][k], swizzled
    __shared__ float4 W1l[64];
    __shared__ float2 st1[64];
    __shared__ float2 st2[64];
    __shared__ float  b2l[64];

    const int tid = threadIdx.x;
    const int lane = tid & 63, wave = tid >> 6;
    const int sbase = blockIdx.x * 64;

    // stage W2 -> bf16 LDS (coalesced 8B global reads; conflict-free swizzled writes)
    for (int e = tid; e < 2048; e += 256) {
        const int o = e >> 5, kp = e & 31;
        float2 wv = *(const float2*)&W2[o * 64 + kp * 2];
        unsigned int pk = (bf16r(wv.y) << 16) | bf16r(wv.x);
        *(unsigned int*)((char*)Wb + swz(o, kp * 4)) = pk;
    }
    if (tid < 64) {
        W1l[tid] = make_float4(W1[tid * 3], W1[tid * 3 + 1], W1[tid * 3 + 2], b1[tid]);
        st1[tid] = make_float2(s1t1[tid], s1t1[64 + tid]);
        st2[tid] = make_float2(s2t2[tid], s2t2[64 + tid]);
        b2l[tid] = b2[tid];
    }
    __syncthreads();   // the only barrier

    // ---- phase A (wave-private): a1 for samples wave*16..+15 ----
    const int sl  = lane & 15;          // sample within wave's 16
    const int cg  = lane >> 4;          // channel group (16 ch each)
    const int row = wave * 16 + sl;     // Ab row
    {
        const int sg = sbase + row;
        const float r0 = rel[sg * 3], r1 = rel[sg * 3 + 1], r2 = rel[sg * 3 + 2];
        unsigned int pk[8];
#pragma unroll
        for (int p = 0; p < 8; ++p) {
            const int c = cg * 16 + p * 2;
            float4 wA = W1l[c];     float2 sA = st1[c];
            float4 wB = W1l[c + 1]; float2 sB = st1[c + 1];
            float a0 = fmaxf(fmaf(sA.x, (wA.x * r0 + wA.y * r1 + wA.z * r2) + wA.w, sA.y), 0.f);
            float a1 = fmaxf(fmaf(sB.x, (wB.x * r0 + wB.y * r1 + wB.z * r2) + wB.w, sB.y), 0.f);
            pk[p] = (bf16r(a1) << 16) | bf16r(a0);
        }
        *(uint4*)((char*)Ab + swz(row, cg * 32))      = make_uint4(pk[0], pk[1], pk[2], pk[3]);
        *(uint4*)((char*)Ab + swz(row, cg * 32 + 16)) = make_uint4(pk[4], pk[5], pk[6], pk[7]);
    }

    // fragment addressing: lane reads 8 contiguous bf16 along k
    const int ko = (lane >> 4) * 16;    // k byte offset within a 64-byte (K=32) half

    // ---- GEMM1: D1T[o][s] ----
    short8 bF0 = *(const short8*)((const char*)Ab + swz(wave * 16 + sl, ko));
    short8 bF1 = *(const short8*)((const char*)Ab + swz(wave * 16 + sl, 64 + ko));
    f32x4 acc1[4];
#pragma unroll
    for (int m = 0; m < 4; ++m) {
        f32x4 acc = {0.f, 0.f, 0.f, 0.f};
        short8 aF0 = *(const short8*)((const char*)Wb + swz(m * 16 + sl, ko));
        acc = __builtin_amdgcn_mfma_f32_16x16x32_bf16(aF0, bF0, acc, 0, 0, 0);
        short8 aF1 = *(const short8*)((const char*)Wb + swz(m * 16 + sl, 64 + ko));
        acc = __builtin_amdgcn_mfma_f32_16x16x32_bf16(aF1, bF1, acc, 0, 0, 0);
        acc1[m] = acc;
    }
    // epilogue 1: a2 = relu(st2*(d1 + b2) + t2); write back in place (own rows only)
#pragma unroll
    for (int m = 0; m < 4; ++m) {
        const int ob = m * 16 + (lane >> 4) * 4;
        unsigned int q0, q1;
        {
            float2 s0 = st2[ob + 0], s1 = st2[ob + 1];
            float v0 = fmaxf(fmaf(s0.x, acc1[m][0] + b2l[ob + 0], s0.y), 0.f);
            float v1 = fmaxf(fmaf(s1.x, acc1[m][1] + b2l[ob + 1], s1.y), 0.f);
            q0 = (bf16r(v1) << 16) | bf16r(v0);
        }
        {
            float2 s2v = st2[ob + 2], s3 = st2[ob + 3];
            float v2 = fmaxf(fmaf(s2v.x, acc1[m][2] + b2l[ob + 2], s2v.y), 0.f);
            float v3 = fmaxf(fmaf(s3.x, acc1[m][3] + b2l[ob + 3], s3.y), 0.f);
            q1 = (bf16r(v3) << 16) | bf16r(v2);
        }
        *(uint2*)((char*)Ab + swz(wave * 16 + sl, ob * 2)) = make_uint2(q0, q1);
    }

    // ---- GEMM2: D2T[o][s] from a2 ----
    short8 cF0 = *(const short8*)((const char*)Ab + swz(wave * 16 + sl, ko));
    short8 cF1 = *(const short8*)((const char*)Ab + swz(wave * 16 + sl, 64 + ko));
    const int qg = sbase / 16 + wave;               // global query of this wave
    const int bb = qg >> 11;
    const int nn = qg & (NPTS - 1);
#pragma unroll
    for (int m = 0; m < 4; ++m) {
        f32x4 acc = {0.f, 0.f, 0.f, 0.f};
        short8 aF0 = *(const short8*)((const char*)Wb + swz(m * 16 + sl, ko));
        acc = __builtin_amdgcn_mfma_f32_16x16x32_bf16(aF0, cF0, acc, 0, 0, 0);
        short8 aF1 = *(const short8*)((const char*)Wb + swz(m * 16 + sl, 64 + ko));
        acc = __builtin_amdgcn_mfma_f32_16x16x32_bf16(aF1, cF1, acc, 0, 0, 0);
        // epilogue 2: + b2, max over the 16 samples (cols = lane&15 group)
        const int ob = m * 16 + (lane >> 4) * 4;
#pragma unroll
        for (int r = 0; r < 4; ++r) {
            float v = acc[r] + b2l[ob + r];
            v = fmaxf(v, __shfl_xor(v, 1, 64));
            v = fmaxf(v, __shfl_xor(v, 2, 64));
            v = fmaxf(v, __shfl_xor(v, 4, 64));
            v = fmaxf(v, __shfl_xor(v, 8, 64));
            if ((lane & 15) == 0)
                out[(size_t)bb * (CH * NPTS) + (ob + r) * NPTS + nn] = v;
        }
    }
}

extern "C" void kernel_launch(void* const* d_in, const int* in_sizes, int n_in,
                              void* d_out, int out_size, void* d_ws, size_t ws_size,
                              hipStream_t stream) {
    (void)in_sizes; (void)n_in; (void)out_size;
    const float* xyz   = (const float*)d_in[0];
    const float* W1    = (const float*)d_in[1];
    const float* b1    = (const float*)d_in[2];
    const float* W2    = (const float*)d_in[3];
    const float* b2    = (const float*)d_in[4];
    const float* gamma = (const float*)d_in[5];
    const float* beta  = (const float*)d_in[6];
    float* out = (float*)d_out;
    float* ws  = (float*)d_ws;

    float* rel    = ws + WS_REL;
    float* s1t1   = ws + WS_S1T1;
    float* s2t2   = ws + WS_S2T2;
    float* part1  = ws + WS_PART1;
    float* Gpart  = ws + WS_GPART;
    float* sapart = ws + WS_SAPART;
    unsigned long long* Gfix = (unsigned long long*)(ws + WS_GFIX);

    const bool big = ws_size >= WS_BIG_FLOATS * 4ull;   // constant -> capture-safe

    knn_rel_kernel<<<dim3(4096), dim3(256), 0, stream>>>(xyz, rel, part1);
    fin1_kernel<<<dim3(1), dim3(256), 0, stream>>>(part1, W1, b1, gamma, beta, s1t1, Gfix);
    if (big) {
        gram_part_kernel<<<dim3(GPART_BLKS), dim3(256), 0, stream>>>(rel, W1, b1, s1t1, Gpart, sapart);
        gred_kernel<<<dim3(65), dim3(256), 0, stream>>>(Gpart, sapart);
        fin2G_part_kernel<<<dim3(1), dim3(1024), 0, stream>>>(Gpart, sapart, W2, b2, gamma, beta, s2t2);
    } else {
        gram_atomic_kernel<<<dim3(256), dim3(256), 0, stream>>>(rel, W1, b1, s1t1, Gfix);
        fin2G_atomic_kernel<<<dim3(1), dim3(1024), 0, stream>>>(Gfix, W2, b2, gamma, beta, s2t2);
    }
    out_kernel<<<dim3(4096), dim3(256), 0, stream>>>(rel, W1, b1, W2, b2, s1t1, s2t2, out);
}

// Round 14
// 117.812 us; speedup vs baseline: 2.6413x; 1.1784x over previous
//
#include <hip/hip_runtime.h>
#include <math.h>

#define BATCH 8
#define NPTS 2048
#define CH 64
#define KNB 16
#define M_SAMPLES (BATCH * NPTS * KNB)   // 262144
#define FIXSCALE 1048576.0               // 2^20 fixed-point (atomic fallback path)
#define GPART_BLKS 512

// ws layout (float offsets) — IDENTICAL to R13:
//   rel    : [0, 786432)         262144 * 3 f32
//   s1t1   : [786432, 786560)
//   s2t2   : [786560, 786688)
//   part1  : [786688, 823552)    4096*9 (knn -> fin1; dead after fin1)
//   BIG path (ws >= 11.67 MB):
//     Gpart : [786688, 2883840)  512 blocks * 4096 f32 (aliases part1)
//     sapart: [2883840, 2916608) 512 * 64 f32
//   SMALL path (fallback, proven R8):
//     Gfix  : [786688, 795008)   4160 u64
#define WS_REL    0
#define WS_S1T1   786432
#define WS_S2T2   786560
#define WS_PART1  786688
#define WS_GFIX   786688
#define WS_GPART  786688
#define WS_SAPART 2883840
#define WS_BIG_FLOATS 2916608ull

#define SURV_CAP 192
#define D2_EPS 1e-4f

typedef __attribute__((ext_vector_type(8))) short short8;
typedef __attribute__((ext_vector_type(4))) float f32x4;

__device__ __forceinline__ unsigned long long u64min(unsigned long long a, unsigned long long b) { return a < b ? a : b; }
__device__ __forceinline__ unsigned long long u64max(unsigned long long a, unsigned long long b) { return a > b ? a : b; }

__device__ __forceinline__ unsigned long long bitonic64(unsigned long long v, int lane) {
#pragma unroll
    for (int k = 2; k <= 64; k <<= 1)
#pragma unroll
        for (int d = k >> 1; d >= 1; d >>= 1) {
            unsigned long long o = __shfl_xor(v, d, 64);
            bool keepmin = (((lane & d) == 0) == ((lane & k) == 0));
            v = keepmin ? u64min(v, o) : u64max(v, o);
        }
    return v;
}

__device__ __forceinline__ unsigned long long cand_key(const float4 pq, const float4 pj, int j, int q) {
    float dot = pq.x * pj.x + pq.y * pj.y + pq.z * pj.z;
    float d2 = fmaxf((pq.w + pj.w) - 2.0f * dot, 0.0f);
    unsigned long long key = ((unsigned long long)__float_as_uint(d2) << 32) | (unsigned int)j;
    return (j == q) ? ~0ull : key;
}

// bf16 round-to-nearest-even
__device__ __forceinline__ unsigned int bf16r(float x) {
    unsigned int u = __float_as_uint(x);
    return (u + 0x7FFFu + ((u >> 16) & 1u)) >> 16;
}
// byte offset into a [64 rows][128 B] bf16 LDS tile, XOR-swizzled (G4: (row&7)<<4)
__device__ __forceinline__ int swz(int row, int kbyte) {
    return (row << 7) + (kbyte ^ ((row & 7) << 4));
}

// ---------------- K1: KNN (R7 structure; pass-2 via ballot compaction) ----------------
__global__ __launch_bounds__(256) void knn_rel_kernel(const float* __restrict__ xyz,
                                                      float* __restrict__ rel,
                                                      float* __restrict__ part1) {
    __shared__ float4 pts[NPTS];
    __shared__ unsigned long long surv[4][SURV_CAP];
    __shared__ float red9[4][9];

    const int b     = blockIdx.x >> 9;
    const int qbase = (blockIdx.x & 511) * 4;
    const int tid   = threadIdx.x;
    const int wave  = tid >> 6, lane = tid & 63;

    const float* xb = xyz + (size_t)b * 3 * NPTS;
    for (int j = tid; j < NPTS; j += 256) {
        float x = xb[j], y = xb[NPTS + j], z = xb[2 * NPTS + j];
        pts[j] = make_float4(x, y, z, (x * x + y * y) + z * z);
    }
    __syncthreads();

    const int q = qbase + wave;
    const float4 pq = pts[q];

    // pass 1: per-lane min key
    unsigned long long lm = ~0ull;
#pragma unroll
    for (int t = 0; t < 32; ++t) {
        const int j = t * 64 + lane;
        lm = u64min(lm, cand_key(pq, pts[j], j, q));
    }
    unsigned long long sorted = bitonic64(lm, lane);
    const float Td2 = __uint_as_float((unsigned int)(__shfl(sorted, 15, 64) >> 32)) + D2_EPS;

    // pass 2: ballot-compacted survivor append (no LDS atomics; order sorted later)
    unsigned int base = 0;
#pragma unroll
    for (int t = 0; t < 32; ++t) {
        const int j = t * 64 + lane;
        unsigned long long key = cand_key(pq, pts[j], j, q);
        float d2 = __uint_as_float((unsigned int)(key >> 32));
        const bool sv = (d2 <= Td2);                    // self has NaN bits -> false
        unsigned long long mask = __ballot(sv);
        if (sv) {
            unsigned int pos = base + (unsigned int)__popcll(mask & ((1ull << lane) - 1ull));
            if (pos < SURV_CAP) surv[wave][pos] = key;
        }
        base += (unsigned int)__popcll(mask);
    }
    const unsigned int total = base;                    // wave-uniform

    // pass 3: top-16. Fast path 16..64 survivors + verified-sorted output.
    unsigned long long wkey = ~0ull;
    bool ok = false;
    if (total >= 16u && total <= 64u) {
        unsigned long long s0 = (lane < (int)total) ? surv[wave][lane] : ~0ull;
        wkey = bitonic64(s0, lane);
        unsigned long long nxt = __shfl_down(wkey, 1, 64);
        ok = __all((lane == 63) || (wkey <= nxt)) != 0;
    }
    if (!ok) {
        unsigned long long last = 0ull; bool first = true;
#pragma unroll 1
        for (int r = 0; r < 16; ++r) {
            unsigned long long m = ~0ull;
#pragma unroll
            for (int t = 0; t < 32; ++t) {
                const int j = t * 64 + lane;
                unsigned long long key = cand_key(pq, pts[j], j, q);
                if (first || key > last) m = u64min(m, key);
            }
#pragma unroll
            for (int d = 1; d < 64; d <<= 1) m = u64min(m, __shfl_xor(m, d, 64));
            if (lane == r) wkey = m;
            last = m; first = false;
        }
    }

    float rr0 = 0.f, rr1 = 0.f, rr2 = 0.f;
    if (lane < 16) {
        const int j = ((int)(unsigned int)wkey) & (NPTS - 1);
        float4 pn = pts[j];
        rr0 = pn.x - pq.x; rr1 = pn.y - pq.y; rr2 = pn.z - pq.z;
        const size_t relbase = ((size_t)(b * NPTS + q)) * (KNB * 3);
        rel[relbase + lane * 3 + 0] = rr0;
        rel[relbase + lane * 3 + 1] = rr1;
        rel[relbase + lane * 3 + 2] = rr2;
    }
    float m0 = rr0, m1 = rr1, m2 = rr2;
    float m3 = rr0 * rr0, m4 = rr0 * rr1, m5 = rr0 * rr2;
    float m6 = rr1 * rr1, m7 = rr1 * rr2, m8 = rr2 * rr2;
#pragma unroll
    for (int d = 1; d < 64; d <<= 1) {
        m0 += __shfl_xor(m0, d, 64); m1 += __shfl_xor(m1, d, 64); m2 += __shfl_xor(m2, d, 64);
        m3 += __shfl_xor(m3, d, 64); m4 += __shfl_xor(m4, d, 64); m5 += __shfl_xor(m5, d, 64);
        m6 += __shfl_xor(m6, d, 64); m7 += __shfl_xor(m7, d, 64); m8 += __shfl_xor(m8, d, 64);
    }
    if (lane == 0) {
        red9[wave][0] = m0; red9[wave][1] = m1; red9[wave][2] = m2;
        red9[wave][3] = m3; red9[wave][4] = m4; red9[wave][5] = m5;
        red9[wave][6] = m6; red9[wave][7] = m7; red9[wave][8] = m8;
    }
    __syncthreads();
    if (tid < 9)
        part1[blockIdx.x * 9 + tid] =
            red9[0][tid] + red9[1][tid] + red9[2][tid] + red9[3][tid];
}

// ---------------- K2: finalize BN1 affine (R13-verbatim) ----------
__global__ __launch_bounds__(256) void fin1_kernel(const float* __restrict__ part1,
                            const float* __restrict__ W1, const float* __restrict__ b1,
                            const float* __restrict__ gamma, const float* __restrict__ beta,
                            float* __restrict__ s1t1, unsigned long long* __restrict__ Gfix) {
    __shared__ double red[9][256];
    __shared__ double sm[9];
    const int t = threadIdx.x;
    double s[9] = {0, 0, 0, 0, 0, 0, 0, 0, 0};
    for (int blk = t; blk < 4096; blk += 256)
#pragma unroll
        for (int v = 0; v < 9; ++v) s[v] += (double)part1[blk * 9 + v];
#pragma unroll
    for (int v = 0; v < 9; ++v) red[v][t] = s[v];
    __syncthreads();
    for (int i = t; i < 4160; i += 256) Gfix[i] = 0ull;
    if (t < 9) {
        double x = 0.0;
        for (int i = 0; i < 256; ++i) x += red[t][i];
        sm[t] = x;
    }
    __syncthreads();
    if (t < 64) {
        const double Md = (double)M_SAMPLES;
        double mu0 = sm[0] / Md, mu1 = sm[1] / Md, mu2 = sm[2] / Md;
        double C00 = sm[3] / Md - mu0 * mu0;
        double C01 = sm[4] / Md - mu0 * mu1;
        double C02 = sm[5] / Md - mu0 * mu2;
        double C11 = sm[6] / Md - mu1 * mu1;
        double C12 = sm[7] / Md - mu1 * mu2;
        double C22 = sm[8] / Md - mu2 * mu2;
        double w0 = (double)W1[t * 3], w1 = (double)W1[t * 3 + 1], w2 = (double)W1[t * 3 + 2];
        double mean = w0 * mu0 + w1 * mu1 + w2 * mu2 + (double)b1[t];
        double var  = w0 * w0 * C00 + w1 * w1 * C11 + w2 * w2 * C22
                    + 2.0 * (w0 * w1 * C01 + w0 * w2 * C02 + w1 * w2 * C12);
        double sc = (double)gamma[t] / sqrt(var + 1e-5);
        s1t1[t]      = (float)sc;
        s1t1[64 + t] = (float)((double)beta[t] - mean * sc);
    }
}

// ======== f32 gram body (atomic fallback only, R13-verbatim) ========
#define GRAM_BODY(NCHUNK)                                                         \
    __shared__ float  A[64][68];                                                  \
    __shared__ float4 W1l[64];                                                    \
    __shared__ float2 st1[64];                                                    \
    const int tid = threadIdx.x;                                                  \
    const int lane = tid & 63, wave = tid >> 6;                                   \
    if (tid < 64) {                                                               \
        W1l[tid] = make_float4(W1[tid * 3], W1[tid * 3 + 1], W1[tid * 3 + 2], b1[tid]); \
        st1[tid] = make_float2(s1t1[tid], s1t1[64 + tid]);                        \
    }                                                                             \
    __syncthreads();                                                              \
    const int i0 = (tid >> 4) * 4, j0 = (tid & 15) * 4;                           \
    float g[4][4];                                                                \
    _Pragma("unroll")                                                             \
    for (int a = 0; a < 4; ++a)                                                   \
        _Pragma("unroll")                                                         \
        for (int c = 0; c < 4; ++c) g[a][c] = 0.f;                                \
    float4 sa4[4];                                                                \
    _Pragma("unroll")                                                             \
    for (int i = 0; i < 4; ++i) sa4[i] = make_float4(0.f, 0.f, 0.f, 0.f);         \
    _Pragma("unroll 1")                                                           \
    for (int ch = 0; ch < NCHUNK; ++ch) {                                         \
        const int s = (blockIdx.x * NCHUNK + ch) * 64 + lane;                     \
        float r0 = rel[s * 3], r1 = rel[s * 3 + 1], r2 = rel[s * 3 + 2];          \
        _Pragma("unroll")                                                         \
        for (int i = 0; i < 4; ++i) {                                             \
            const int c0 = wave * 16 + i * 4;                                     \
            float4 av;                                                            \
            { float4 w = W1l[c0];     float2 st = st1[c0];                        \
              av.x = fmaxf(fmaf(st.x, (w.x*r0 + w.y*r1 + w.z*r2) + w.w, st.y), 0.f); } \
            { float4 w = W1l[c0 + 1]; float2 st = st1[c0 + 1];                    \
              av.y = fmaxf(fmaf(st.x, (w.x*r0 + w.y*r1 + w.z*r2) + w.w, st.y), 0.f); } \
            { float4 w = W1l[c0 + 2]; float2 st = st1[c0 + 2];                    \
              av.z = fmaxf(fmaf(st.x, (w.x*r0 + w.y*r1 + w.z*r2) + w.w, st.y), 0.f); } \
            { float4 w = W1l[c0 + 3]; float2 st = st1[c0 + 3];                    \
              av.w = fmaxf(fmaf(st.x, (w.x*r0 + w.y*r1 + w.z*r2) + w.w, st.y), 0.f); } \
            *(float4*)&A[lane][c0] = av;                                          \
            sa4[i].x += av.x; sa4[i].y += av.y; sa4[i].z += av.z; sa4[i].w += av.w; \
        }                                                                         \
        __syncthreads();                                                          \
        _Pragma("unroll 4")                                                       \
        for (int sl = 0; sl < 64; ++sl) {                                         \
            float4 ai = *(const float4*)&A[sl][i0];                               \
            float4 aj = *(const float4*)&A[sl][j0];                               \
            g[0][0] = fmaf(ai.x, aj.x, g[0][0]); g[0][1] = fmaf(ai.x, aj.y, g[0][1]); \
            g[0][2] = fmaf(ai.x, aj.z, g[0][2]); g[0][3] = fmaf(ai.x, aj.w, g[0][3]); \
            g[1][0] = fmaf(ai.y, aj.x, g[1][0]); g[1][1] = fmaf(ai.y, aj.y, g[1][1]); \
            g[1][2] = fmaf(ai.y, aj.z, g[1][2]); g[1][3] = fmaf(ai.y, aj.w, g[1][3]); \
            g[2][0] = fmaf(ai.z, aj.x, g[2][0]); g[2][1] = fmaf(ai.z, aj.y, g[2][1]); \
            g[2][2] = fmaf(ai.z, aj.z, g[2][2]); g[2][3] = fmaf(ai.z, aj.w, g[2][3]); \
            g[3][0] = fmaf(ai.w, aj.x, g[3][0]); g[3][1] = fmaf(ai.w, aj.y, g[3][1]); \
            g[3][2] = fmaf(ai.w, aj.z, g[3][2]); g[3][3] = fmaf(ai.w, aj.w, g[3][3]); \
        }                                                                         \
        __syncthreads();                                                          \
    }                                                                             \
    _Pragma("unroll")                                                             \
    for (int i = 0; i < 4; ++i) {                                                 \
        float4 v = sa4[i];                                                        \
        _Pragma("unroll")                                                         \
        for (int d = 1; d < 64; d <<= 1) {                                        \
            v.x += __shfl_xor(v.x, d, 64); v.y += __shfl_xor(v.y, d, 64);         \
            v.z += __shfl_xor(v.z, d, 64); v.w += __shfl_xor(v.w, d, 64);         \
        }                                                                         \
        sa4[i] = v;                                                               \
    }

// ---------------- K3a (BIG): per-block G partials via bf16 MFMA ----------------
// grid 512, block 256 = 4 waves; 8 chunks of 64 samples. a-tile channel-major
// bf16 Ab[c][s] (swizzled); G tile-row per wave via mfma_f32_16x16x32_bf16,
// fragment addressing identical to R13's proven out_kernel. sa stays exact f32.
__global__ __launch_bounds__(256) void gram_part_kernel(const float* __restrict__ rel,
        const float* __restrict__ W1, const float* __restrict__ b1,
        const float* __restrict__ s1t1,
        float* __restrict__ Gpart, float* __restrict__ sapart) {
    __shared__ unsigned short Ab[64 * 64];   // [c][s] bf16, swizzled
    __shared__ float4 W1l[64];
    __shared__ float2 st1[64];
    const int tid = threadIdx.x;
    const int lane = tid & 63, wave = tid >> 6;
    if (tid < 64) {
        W1l[tid] = make_float4(W1[tid * 3], W1[tid * 3 + 1], W1[tid * 3 + 2], b1[tid]);
        st1[tid] = make_float2(s1t1[tid], s1t1[64 + tid]);
    }
    __syncthreads();

    const int sl = lane & 15;
    const int ko = (lane >> 4) * 16;
    f32x4 acc[4];
#pragma unroll
    for (int n = 0; n < 4; ++n) acc[n] = (f32x4){0.f, 0.f, 0.f, 0.f};
    float4 sa4[4];
#pragma unroll
    for (int i = 0; i < 4; ++i) sa4[i] = make_float4(0.f, 0.f, 0.f, 0.f);

#pragma unroll 1
    for (int ch = 0; ch < 8; ++ch) {
        // phase 1: lane = sample, wave = its 16-channel block; write bf16 [c][s]
        const int s = (blockIdx.x * 8 + ch) * 64 + lane;
        const float r0 = rel[s * 3], r1 = rel[s * 3 + 1], r2 = rel[s * 3 + 2];
#pragma unroll
        for (int i = 0; i < 4; ++i) {
            const int c0 = wave * 16 + i * 4;
            float av[4];
#pragma unroll
            for (int u = 0; u < 4; ++u) {
                float4 w = W1l[c0 + u]; float2 st = st1[c0 + u];
                av[u] = fmaxf(fmaf(st.x, (w.x * r0 + w.y * r1 + w.z * r2) + w.w, st.y), 0.f);
            }
            sa4[i].x += av[0]; sa4[i].y += av[1]; sa4[i].z += av[2]; sa4[i].w += av[3];
#pragma unroll
            for (int u = 0; u < 4; ++u)
                *(unsigned short*)((char*)Ab + swz(c0 + u, lane * 2)) =
                    (unsigned short)bf16r(av[u]);
        }
        __syncthreads();
        // phase 2: wave w owns G tile-row w; D[c1][c2] += sum_s a[c1][s] a[c2][s]
        short8 aF0 = *(const short8*)((const char*)Ab + swz(wave * 16 + sl, ko));
        short8 aF1 = *(const short8*)((const char*)Ab + swz(wave * 16 + sl, 64 + ko));
#pragma unroll
        for (int n = 0; n < 4; ++n) {
            short8 b0 = *(const short8*)((const char*)Ab + swz(n * 16 + sl, ko));
            short8 b1 = *(const short8*)((const char*)Ab + swz(n * 16 + sl, 64 + ko));
            acc[n] = __builtin_amdgcn_mfma_f32_16x16x32_bf16(aF0, b0, acc[n], 0, 0, 0);
            acc[n] = __builtin_amdgcn_mfma_f32_16x16x32_bf16(aF1, b1, acc[n], 0, 0, 0);
        }
        __syncthreads();
    }
    // write G partial: D mapping col=lane&15, row=(lane>>4)*4+reg (m89)
    float* Gp = Gpart + (size_t)blockIdx.x * 4096;
#pragma unroll
    for (int n = 0; n < 4; ++n)
#pragma unroll
        for (int r = 0; r < 4; ++r) {
            const int c1 = wave * 16 + (lane >> 4) * 4 + r;
            const int c2 = n * 16 + sl;
            Gp[c1 * 64 + c2] = acc[n][r];
        }
#pragma unroll
    for (int i = 0; i < 4; ++i) {
        float4 v = sa4[i];
#pragma unroll
        for (int d = 1; d < 64; d <<= 1) {
            v.x += __shfl_xor(v.x, d, 64); v.y += __shfl_xor(v.y, d, 64);
            v.z += __shfl_xor(v.z, d, 64); v.w += __shfl_xor(v.w, d, 64);
        }
        if (lane == 0) {
            float* sp = sapart + (size_t)blockIdx.x * 64 + wave * 16 + i * 4;
            sp[0] = v.x; sp[1] = v.y; sp[2] = v.z; sp[3] = v.w;
        }
    }
}

// ---------------- K3a2 (BIG): parallel 512->1 reduction (R13-verbatim) --------
__global__ __launch_bounds__(256) void gred_kernel(float* __restrict__ Gpart,
                                                   float* __restrict__ sapart) {
    __shared__ double red[4][64];
    const int tid = threadIdx.x;
    const int sub = tid & 63;
    const int j   = tid >> 6;
    const int e   = blockIdx.x * 64 + sub;
    double acc = 0.0;
    if (e < 4096) {
        const float* src = Gpart + e;
        for (int p = j * 128; p < (j + 1) * 128; ++p)
            acc += (double)src[(size_t)p * 4096];
    } else if (e < 4160) {
        const float* src = sapart + (e - 4096);
        for (int p = j * 128; p < (j + 1) * 128; ++p)
            acc += (double)src[(size_t)p * 64];
    }
    red[j][sub] = acc;
    __syncthreads();
    if (j == 0) {
        double t = ((red[0][sub] + red[1][sub]) + red[2][sub]) + red[3][sub];
        if (e < 4096)      Gpart[(size_t)511 * 4096 + e] = (float)t;
        else if (e < 4160) sapart[(size_t)511 * 64 + (e - 4096)] = (float)t;
    }
}

// ---------------- K3b (SMALL fallback, proven R8) ------------
__global__ __launch_bounds__(256) void gram_atomic_kernel(const float* __restrict__ rel,
        const float* __restrict__ W1, const float* __restrict__ b1,
        const float* __restrict__ s1t1, unsigned long long* __restrict__ Gfix) {
    GRAM_BODY(16)
#pragma unroll
    for (int a = 0; a < 4; ++a)
#pragma unroll
        for (int c = 0; c < 4; ++c)
            atomicAdd(&Gfix[(i0 + a) * 64 + (j0 + c)],
                      (unsigned long long)((double)g[a][c] * FIXSCALE));
    if (lane == 0) {
#pragma unroll
        for (int i = 0; i < 4; ++i) {
            const int c0 = wave * 16 + i * 4;
            atomicAdd(&Gfix[4096 + c0 + 0], (unsigned long long)((double)sa4[i].x * FIXSCALE));
            atomicAdd(&Gfix[4096 + c0 + 1], (unsigned long long)((double)sa4[i].y * FIXSCALE));
            atomicAdd(&Gfix[4096 + c0 + 2], (unsigned long long)((double)sa4[i].z * FIXSCALE));
            atomicAdd(&Gfix[4096 + c0 + 3], (unsigned long long)((double)sa4[i].w * FIXSCALE));
        }
    }
}

// ======== shared fin2G tail (R13-verbatim) ========
#define FIN2G_TAIL                                                                \
    const int o = tid & 63, part = tid >> 6;                                      \
    float partial = 0.f;                                                          \
    _Pragma("unroll")                                                             \
    for (int ii = 0; ii < 4; ++ii) {                                              \
        const int i = part * 4 + ii;                                              \
        float t2 = 0.f;                                                           \
        _Pragma("unroll")                                                         \
        for (int j = 0; j < 64; j += 4) {                                         \
            float4 wj = *(const float4*)&w2s[o][j];                               \
            float4 gj = *(const float4*)&Gs[i][j];                                \
            t2 = fmaf(wj.x, gj.x, t2); t2 = fmaf(wj.y, gj.y, t2);                 \
            t2 = fmaf(wj.z, gj.z, t2); t2 = fmaf(wj.w, gj.w, t2);                 \
        }                                                                         \
        partial = fmaf(w2s[o][i], t2, partial);                                   \
    }                                                                             \
    red[part][o] = partial;                                                       \
    __syncthreads();                                                              \
    if (tid < 64) {                                                               \
        double qf = 0.0;                                                          \
        _Pragma("unroll")                                                         \
        for (int p = 0; p < 16; ++p) qf += (double)red[p][tid];                   \
        double SA = 0.0;                                                          \
        for (int c = 0; c < 64; ++c) SA += (double)w2s[tid][c] * (double)sa_s[c]; \
        const double Md = (double)M_SAMPLES;                                      \
        double mean = SA / Md + (double)b2[tid];                                  \
        double var  = qf / Md - (SA / Md) * (SA / Md);                            \
        double sc = (double)gamma[tid] / sqrt(var + 1e-5);                        \
        s2t2[tid]      = (float)sc;                                               \
        s2t2[64 + tid] = (float)((double)beta[tid] - mean * sc);                  \
    }

// ---------------- K4a (BIG): finalize from reduced row 511 (R13-verbatim) -------------
__global__ __launch_bounds__(1024) void fin2G_part_kernel(const float* __restrict__ Gpart,
                            const float* __restrict__ sapart,
                            const float* __restrict__ W2, const float* __restrict__ b2,
                            const float* __restrict__ gamma, const float* __restrict__ beta,
                            float* __restrict__ s2t2) {
    __shared__ float Gs[64][68];
    __shared__ float w2s[64][68];
    __shared__ float sa_s[64];
    __shared__ float red[16][64];
    const int tid = threadIdx.x;
    for (int i = tid; i < 4096; i += 1024) {
        Gs[i >> 6][i & 63]  = Gpart[(size_t)511 * 4096 + i];
        w2s[i >> 6][i & 63] = W2[i];
    }
    if (tid < 64) sa_s[tid] = sapart[(size_t)511 * 64 + tid];
    __syncthreads();
    FIN2G_TAIL
}

// ---------------- K4b (SMALL fallback, proven R8) ----------------
__global__ __launch_bounds__(1024) void fin2G_atomic_kernel(const unsigned long long* __restrict__ Gfix,
                            const float* __restrict__ W2, const float* __restrict__ b2,
                            const float* __restrict__ gamma, const float* __restrict__ beta,
                            float* __restrict__ s2t2) {
    __shared__ float Gs[64][68];
    __shared__ float w2s[64][68];
    __shared__ float sa_s[64];
    __shared__ float red[16][64];
    const int tid = threadIdx.x;
    const double INV = 1.0 / FIXSCALE;
    for (int i = tid; i < 4096; i += 1024) {
        Gs[i >> 6][i & 63]  = (float)((double)Gfix[i] * INV);
        w2s[i >> 6][i & 63] = W2[i];
    }
    if (tid < 64) sa_s[tid] = (float)((double)Gfix[4096 + tid] * INV);
    __syncthreads();
    FIN2G_TAIL
}

// ---------------- K5: MFMA bf16 block-GEMM chain + max over k (R13-verbatim) ----------
__global__ __launch_bounds__(256) void out_kernel(const float* __restrict__ rel,
        const float* __restrict__ W1, const float* __restrict__ b1,
        const float* __restrict__ W2, const float* __restrict__ b2,
        const float* __restrict__ s1t1, const float* __restrict__ s2t2,
        float* __restrict__ out) {
    __shared__ unsigned short Wb[64 * 64];
    __shared__ unsigned short Ab[64 * 64];
    __shared__ float4 W1l[64];
    __shared__ float2 st1[64];
    __shared__ float2 st2[64];
    __shared__ float  b2l[64];

    const int tid = threadIdx.x;
    const int lane = tid & 63, wave = tid >> 6;
    const int sbase = blockIdx.x * 64;

    for (int e = tid; e < 2048; e += 256) {
        const int o = e >> 5, kp = e & 31;
        float2 wv = *(const float2*)&W2[o * 64 + kp * 2];
        unsigned int pk = (bf16r(wv.y) << 16) | bf16r(wv.x);
        *(unsigned int*)((char*)Wb + swz(o, kp * 4)) = pk;
    }
    if (tid < 64) {
        W1l[tid] = make_float4(W1[tid * 3], W1[tid * 3 + 1], W1[tid * 3 + 2], b1[tid]);
        st1[tid] = make_float2(s1t1[tid], s1t1[64 + tid]);
        st2[tid] = make_float2(s2t2[tid], s2t2[64 + tid]);
        b2l[tid] = b2[tid];
    }
    __syncthreads();

    const int sl  = lane & 15;
    const int cg  = lane >> 4;
    const int row = wave * 16 + sl;
    {
        const int sg = sbase + row;
        const float r0 = rel[sg * 3], r1 = rel[sg * 3 + 1], r2 = rel[sg * 3 + 2];
        unsigned int pk[8];
#pragma unroll
        for (int p = 0; p < 8; ++p) {
            const int c = cg * 16 + p * 2;
            float4 wA = W1l[c];     float2 sA = st1[c];
            float4 wB = W1l[c + 1]; float2 sB = st1[c + 1];
            float a0 = fmaxf(fmaf(sA.x, (wA.x * r0 + wA.y * r1 + wA.z * r2) + wA.w, sA.y), 0.f);
            float a1 = fmaxf(fmaf(sB.x, (wB.x * r0 + wB.y * r1 + wB.z * r2) + wB.w, sB.y), 0.f);
            pk[p] = (bf16r(a1) << 16) | bf16r(a0);
        }
        *(uint4*)((char*)Ab + swz(row, cg * 32))      = make_uint4(pk[0], pk[1], pk[2], pk[3]);
        *(uint4*)((char*)Ab + swz(row, cg * 32 + 16)) = make_uint4(pk[4], pk[5], pk[6], pk[7]);
    }

    const int ko = (lane >> 4) * 16;

    short8 bF0 = *(const short8*)((const char*)Ab + swz(wave * 16 + sl, ko));
    short8 bF1 = *(const short8*)((const char*)Ab + swz(wave * 16 + sl, 64 + ko));
    f32x4 acc1[4];
#pragma unroll
    for (int m = 0; m < 4; ++m) {
        f32x4 acc = {0.f, 0.f, 0.f, 0.f};
        short8 aF0 = *(const short8*)((const char*)Wb + swz(m * 16 + sl, ko));
        acc = __builtin_amdgcn_mfma_f32_16x16x32_bf16(aF0, bF0, acc, 0, 0, 0);
        short8 aF1 = *(const short8*)((const char*)Wb + swz(m * 16 + sl, 64 + ko));
        acc = __builtin_amdgcn_mfma_f32_16x16x32_bf16(aF1, bF1, acc, 0, 0, 0);
        acc1[m] = acc;
    }
#pragma unroll
    for (int m = 0; m < 4; ++m) {
        const int ob = m * 16 + (lane >> 4) * 4;
        unsigned int q0, q1;
        {
            float2 s0 = st2[ob + 0], s1 = st2[ob + 1];
            float v0 = fmaxf(fmaf(s0.x, acc1[m][0] + b2l[ob + 0], s0.y), 0.f);
            float v1 = fmaxf(fmaf(s1.x, acc1[m][1] + b2l[ob + 1], s1.y), 0.f);
            q0 = (bf16r(v1) << 16) | bf16r(v0);
        }
        {
            float2 s2v = st2[ob + 2], s3 = st2[ob + 3];
            float v2 = fmaxf(fmaf(s2v.x, acc1[m][2] + b2l[ob + 2], s2v.y), 0.f);
            float v3 = fmaxf(fmaf(s3.x, acc1[m][3] + b2l[ob + 3], s3.y), 0.f);
            q1 = (bf16r(v3) << 16) | bf16r(v2);
        }
        *(uint2*)((char*)Ab + swz(wave * 16 + sl, ob * 2)) = make_uint2(q0, q1);
    }

    short8 cF0 = *(const short8*)((const char*)Ab + swz(wave * 16 + sl, ko));
    short8 cF1 = *(const short8*)((const char*)Ab + swz(wave * 16 + sl, 64 + ko));
    const int qg = sbase / 16 + wave;
    const int bb = qg >> 11;
    const int nn = qg & (NPTS - 1);
#pragma unroll
    for (int m = 0; m < 4; ++m) {
        f32x4 acc = {0.f, 0.f, 0.f, 0.f};
        short8 aF0 = *(const short8*)((const char*)Wb + swz(m * 16 + sl, ko));
        acc = __builtin_amdgcn_mfma_f32_16x16x32_bf16(aF0, cF0, acc, 0, 0, 0);
        short8 aF1 = *(const short8*)((const char*)Wb + swz(m * 16 + sl, 64 + ko));
        acc = __builtin_amdgcn_mfma_f32_16x16x32_bf16(aF1, cF1, acc, 0, 0, 0);
        const int ob = m * 16 + (lane >> 4) * 4;
#pragma unroll
        for (int r = 0; r < 4; ++r) {
            float v = acc[r] + b2l[ob + r];
            v = fmaxf(v, __shfl_xor(v, 1, 64));
            v = fmaxf(v, __shfl_xor(v, 2, 64));
            v = fmaxf(v, __shfl_xor(v, 4, 64));
            v = fmaxf(v, __shfl_xor(v, 8, 64));
            if ((lane & 15) == 0)
                out[(size_t)bb * (CH * NPTS) + (ob + r) * NPTS + nn] = v;
        }
    }
}

extern "C" void kernel_launch(void* const* d_in, const int* in_sizes, int n_in,
                              void* d_out, int out_size, void* d_ws, size_t ws_size,
                              hipStream_t stream) {
    (void)in_sizes; (void)n_in; (void)out_size;
    const float* xyz   = (const float*)d_in[0];
    const float* W1    = (const float*)d_in[1];
    const float* b1    = (const float*)d_in[2];
    const float* W2    = (const float*)d_in[3];
    const float* b2    = (const float*)d_in[4];
    const float* gamma = (const float*)d_in[5];
    const float* beta  = (const float*)d_in[6];
    float* out = (float*)d_out;
    float* ws  = (float*)d_ws;

    float* rel    = ws + WS_REL;
    float* s1t1   = ws + WS_S1T1;
    float* s2t2   = ws + WS_S2T2;
    float* part1  = ws + WS_PART1;
    float* Gpart  = ws + WS_GPART;
    float* sapart = ws + WS_SAPART;
    unsigned long long* Gfix = (unsigned long long*)(ws + WS_GFIX);

    const bool big = ws_size >= WS_BIG_FLOATS * 4ull;   // constant -> capture-safe

    knn_rel_kernel<<<dim3(4096), dim3(256), 0, stream>>>(xyz, rel, part1);
    fin1_kernel<<<dim3(1), dim3(256), 0, stream>>>(part1, W1, b1, gamma, beta, s1t1, Gfix);
    if (big) {
        gram_part_kernel<<<dim3(GPART_BLKS), dim3(256), 0, stream>>>(rel, W1, b1, s1t1, Gpart, sapart);
        gred_kernel<<<dim3(65), dim3(256), 0, stream>>>(Gpart, sapart);
        fin2G_part_kernel<<<dim3(1), dim3(1024), 0, stream>>>(Gpart, sapart, W2, b2, gamma, beta, s2t2);
    } else {
        gram_atomic_kernel<<<dim3(256), dim3(256), 0, stream>>>(rel, W1, b1, s1t1, Gfix);
        fin2G_atomic_kernel<<<dim3(1), dim3(1024), 0, stream>>>(Gfix, W2, b2, gamma, beta, s2t2);
    }
    out_kernel<<<dim3(4096), dim3(256), 0, stream>>>(rel, W1, b1, W2, b2, s1t1, s2t2, out);
}

// Round 15
// 106.377 us; speedup vs baseline: 2.9252x; 1.1075x over previous
//
#include <hip/hip_runtime.h>
#include <math.h>

#define BATCH 8
#define NPTS 2048
#define CH 64
#define KNB 16
#define M_SAMPLES (BATCH * NPTS * KNB)   // 262144
#define FIXSCALE 1048576.0               // 2^20 fixed-point (atomic fallback path)
#define GPART_BLKS 512

// ws layout (float offsets) — IDENTICAL to R14:
//   rel    : [0, 786432)         262144 * 3 f32
//   s1t1   : [786432, 786560)
//   s2t2   : [786560, 786688)
//   part1  : [786688, 823552)    4096*9 (knn -> fin1; dead after fin1)
//   BIG path (ws >= 11.67 MB):
//     Gpart : [786688, 2883840)  512 blocks * 4096 f32 (aliases part1)
//     sapart: [2883840, 2916608) 512 * 64 f32
//   SMALL path (fallback, proven R8):
//     Gfix  : [786688, 795008)   4160 u64
#define WS_REL    0
#define WS_S1T1   786432
#define WS_S2T2   786560
#define WS_PART1  786688
#define WS_GFIX   786688
#define WS_GPART  786688
#define WS_SAPART 2883840
#define WS_BIG_FLOATS 2916608ull

#define SURV_CAP 192

typedef __attribute__((ext_vector_type(8))) short short8;
typedef __attribute__((ext_vector_type(4))) float f32x4;

__device__ __forceinline__ unsigned long long u64min(unsigned long long a, unsigned long long b) { return a < b ? a : b; }
__device__ __forceinline__ unsigned long long u64max(unsigned long long a, unsigned long long b) { return a > b ? a : b; }

__device__ __forceinline__ unsigned long long bitonic64(unsigned long long v, int lane) {
#pragma unroll
    for (int k = 2; k <= 64; k <<= 1)
#pragma unroll
        for (int d = k >> 1; d >= 1; d >>= 1) {
            unsigned long long o = __shfl_xor(v, d, 64);
            bool keepmin = (((lane & d) == 0) == ((lane & k) == 0));
            v = keepmin ? u64min(v, o) : u64max(v, o);
        }
    return v;
}

// 32-bit bitonic sort across 64 lanes (u32 keys; non-negative floats sort as uints)
__device__ __forceinline__ unsigned int bitonic64_u32(unsigned int v, int lane) {
#pragma unroll
    for (int k = 2; k <= 64; k <<= 1)
#pragma unroll
        for (int d = k >> 1; d >= 1; d >>= 1) {
            unsigned int o = __shfl_xor(v, d, 64);
            bool keepmin = (((lane & d) == 0) == ((lane & k) == 0));
            unsigned int mn = o < v ? o : v, mx = o > v ? o : v;
            v = keepmin ? mn : mx;
        }
    return v;
}

__device__ __forceinline__ unsigned long long cand_key(const float4 pq, const float4 pj, int j, int q) {
    float dot = pq.x * pj.x + pq.y * pj.y + pq.z * pj.z;
    float d2 = fmaxf((pq.w + pj.w) - 2.0f * dot, 0.0f);
    unsigned long long key = ((unsigned long long)__float_as_uint(d2) << 32) | (unsigned int)j;
    return (j == q) ? ~0ull : key;
}

// bf16 round-to-nearest-even
__device__ __forceinline__ unsigned int bf16r(float x) {
    unsigned int u = __float_as_uint(x);
    return (u + 0x7FFFu + ((u >> 16) & 1u)) >> 16;
}
// byte offset into a [64 rows][128 B] bf16 LDS tile, XOR-swizzled (G4: (row&7)<<4)
__device__ __forceinline__ int swz(int row, int kbyte) {
    return (row << 7) + (kbyte ^ ((row & 7) << 4));
}

// ---------------- K1: KNN — d2 register cache + u32 threshold sort ----------------
// Pass1 stores all 32 per-lane d2 in VGPRs; pass2 is register-only (exact-consistent
// threshold: >=16 survivors GUARANTEED, no fp-contraction slack needed).
__global__ __launch_bounds__(256) void knn_rel_kernel(const float* __restrict__ xyz,
                                                      float* __restrict__ rel,
                                                      float* __restrict__ part1) {
    __shared__ float4 pts[NPTS];
    __shared__ unsigned long long surv[4][SURV_CAP];
    __shared__ float red9[4][9];

    const int b     = blockIdx.x >> 9;
    const int qbase = (blockIdx.x & 511) * 4;
    const int tid   = threadIdx.x;
    const int wave  = tid >> 6, lane = tid & 63;

    const float* xb = xyz + (size_t)b * 3 * NPTS;
    for (int j = tid; j < NPTS; j += 256) {
        float x = xb[j], y = xb[NPTS + j], z = xb[2 * NPTS + j];
        pts[j] = make_float4(x, y, z, (x * x + y * y) + z * z);
    }
    __syncthreads();

    const int q = qbase + wave;
    const float4 pq = pts[q];

    // pass 1: compute & cache d2 for this lane's 32 candidates; f32 lane-min
    float d2s[32];
    float lmd = INFINITY;
#pragma unroll
    for (int t = 0; t < 32; ++t) {
        const int j = t * 64 + lane;
        float4 pj = pts[j];
        float dot = pq.x * pj.x + pq.y * pj.y + pq.z * pj.z;
        float d2 = fmaxf((pq.w + pj.w) - 2.0f * dot, 0.0f);
        d2 = (j == q) ? INFINITY : d2;      // self excluded
        d2s[t] = d2;
        lmd = fminf(lmd, d2);
    }
    // T = 16th smallest lane-min (u32 sort; exact vs the cached values)
    unsigned int sortedd = bitonic64_u32(__float_as_uint(lmd), lane);
    const float Td2 = __uint_as_float((unsigned int)__shfl((int)sortedd, 15, 64));

    // pass 2: register-only survivor test; ballot compaction into LDS
    unsigned int base = 0;
#pragma unroll
    for (int t = 0; t < 32; ++t) {
        const bool sv = (d2s[t] <= Td2);    // INF/self never survives
        unsigned long long mask = __ballot(sv);
        if (sv) {
            const int j = t * 64 + lane;
            unsigned int pos = base + (unsigned int)__popcll(mask & ((1ull << lane) - 1ull));
            if (pos < SURV_CAP)
                surv[wave][pos] =
                    ((unsigned long long)__float_as_uint(d2s[t]) << 32) | (unsigned int)j;
        }
        base += (unsigned int)__popcll(mask);
    }
    const unsigned int total = base;        // wave-uniform; >=16 guaranteed

    // pass 3: top-16. Fast path <=64 survivors + verified-sorted output.
    unsigned long long wkey = ~0ull;
    bool ok = false;
    if (total <= 64u) {
        unsigned long long s0 = (lane < (int)total) ? surv[wave][lane] : ~0ull;
        wkey = bitonic64(s0, lane);
        unsigned long long nxt = __shfl_down(wkey, 1, 64);
        ok = __all((lane == 63) || (wkey <= nxt)) != 0;
    }
    if (!ok) {
        // exact chained extract-min fallback (self-consistent recompute)
        unsigned long long last = 0ull; bool first = true;
#pragma unroll 1
        for (int r = 0; r < 16; ++r) {
            unsigned long long m = ~0ull;
#pragma unroll
            for (int t = 0; t < 32; ++t) {
                const int j = t * 64 + lane;
                unsigned long long key = cand_key(pq, pts[j], j, q);
                if (first || key > last) m = u64min(m, key);
            }
#pragma unroll
            for (int d = 1; d < 64; d <<= 1) m = u64min(m, __shfl_xor(m, d, 64));
            if (lane == r) wkey = m;
            last = m; first = false;
        }
    }

    float rr0 = 0.f, rr1 = 0.f, rr2 = 0.f;
    if (lane < 16) {
        const int j = ((int)(unsigned int)wkey) & (NPTS - 1);
        float4 pn = pts[j];
        rr0 = pn.x - pq.x; rr1 = pn.y - pq.y; rr2 = pn.z - pq.z;
        const size_t relbase = ((size_t)(b * NPTS + q)) * (KNB * 3);
        rel[relbase + lane * 3 + 0] = rr0;
        rel[relbase + lane * 3 + 1] = rr1;
        rel[relbase + lane * 3 + 2] = rr2;
    }
    // BN1 moments: data lives in lanes 0..15 -> 4-step reduce suffices (lane 0 total)
    float m0 = rr0, m1 = rr1, m2 = rr2;
    float m3 = rr0 * rr0, m4 = rr0 * rr1, m5 = rr0 * rr2;
    float m6 = rr1 * rr1, m7 = rr1 * rr2, m8 = rr2 * rr2;
#pragma unroll
    for (int d = 1; d < 16; d <<= 1) {
        m0 += __shfl_xor(m0, d, 64); m1 += __shfl_xor(m1, d, 64); m2 += __shfl_xor(m2, d, 64);
        m3 += __shfl_xor(m3, d, 64); m4 += __shfl_xor(m4, d, 64); m5 += __shfl_xor(m5, d, 64);
        m6 += __shfl_xor(m6, d, 64); m7 += __shfl_xor(m7, d, 64); m8 += __shfl_xor(m8, d, 64);
    }
    if (lane == 0) {
        red9[wave][0] = m0; red9[wave][1] = m1; red9[wave][2] = m2;
        red9[wave][3] = m3; red9[wave][4] = m4; red9[wave][5] = m5;
        red9[wave][6] = m6; red9[wave][7] = m7; red9[wave][8] = m8;
    }
    __syncthreads();
    if (tid < 9)
        part1[blockIdx.x * 9 + tid] =
            red9[0][tid] + red9[1][tid] + red9[2][tid] + red9[3][tid];
}

// ---------------- K2: finalize BN1 affine (R14-verbatim) ----------
__global__ __launch_bounds__(256) void fin1_kernel(const float* __restrict__ part1,
                            const float* __restrict__ W1, const float* __restrict__ b1,
                            const float* __restrict__ gamma, const float* __restrict__ beta,
                            float* __restrict__ s1t1, unsigned long long* __restrict__ Gfix) {
    __shared__ double red[9][256];
    __shared__ double sm[9];
    const int t = threadIdx.x;
    double s[9] = {0, 0, 0, 0, 0, 0, 0, 0, 0};
    for (int blk = t; blk < 4096; blk += 256)
#pragma unroll
        for (int v = 0; v < 9; ++v) s[v] += (double)part1[blk * 9 + v];
#pragma unroll
    for (int v = 0; v < 9; ++v) red[v][t] = s[v];
    __syncthreads();
    for (int i = t; i < 4160; i += 256) Gfix[i] = 0ull;
    if (t < 9) {
        double x = 0.0;
        for (int i = 0; i < 256; ++i) x += red[t][i];
        sm[t] = x;
    }
    __syncthreads();
    if (t < 64) {
        const double Md = (double)M_SAMPLES;
        double mu0 = sm[0] / Md, mu1 = sm[1] / Md, mu2 = sm[2] / Md;
        double C00 = sm[3] / Md - mu0 * mu0;
        double C01 = sm[4] / Md - mu0 * mu1;
        double C02 = sm[5] / Md - mu0 * mu2;
        double C11 = sm[6] / Md - mu1 * mu1;
        double C12 = sm[7] / Md - mu1 * mu2;
        double C22 = sm[8] / Md - mu2 * mu2;
        double w0 = (double)W1[t * 3], w1 = (double)W1[t * 3 + 1], w2 = (double)W1[t * 3 + 2];
        double mean = w0 * mu0 + w1 * mu1 + w2 * mu2 + (double)b1[t];
        double var  = w0 * w0 * C00 + w1 * w1 * C11 + w2 * w2 * C22
                    + 2.0 * (w0 * w1 * C01 + w0 * w2 * C02 + w1 * w2 * C12);
        double sc = (double)gamma[t] / sqrt(var + 1e-5);
        s1t1[t]      = (float)sc;
        s1t1[64 + t] = (float)((double)beta[t] - mean * sc);
    }
}

// ======== f32 gram body (atomic fallback only, R14-verbatim) ========
#define GRAM_BODY(NCHUNK)                                                         \
    __shared__ float  A[64][68];                                                  \
    __shared__ float4 W1l[64];                                                    \
    __shared__ float2 st1[64];                                                    \
    const int tid = threadIdx.x;                                                  \
    const int lane = tid & 63, wave = tid >> 6;                                   \
    if (tid < 64) {                                                               \
        W1l[tid] = make_float4(W1[tid * 3], W1[tid * 3 + 1], W1[tid * 3 + 2], b1[tid]); \
        st1[tid] = make_float2(s1t1[tid], s1t1[64 + tid]);                        \
    }                                                                             \
    __syncthreads();                                                              \
    const int i0 = (tid >> 4) * 4, j0 = (tid & 15) * 4;                           \
    float g[4][4];                                                                \
    _Pragma("unroll")                                                             \
    for (int a = 0; a < 4; ++a)                                                   \
        _Pragma("unroll")                                                         \
        for (int c = 0; c < 4; ++c) g[a][c] = 0.f;                                \
    float4 sa4[4];                                                                \
    _Pragma("unroll")                                                             \
    for (int i = 0; i < 4; ++i) sa4[i] = make_float4(0.f, 0.f, 0.f, 0.f);         \
    _Pragma("unroll 1")                                                           \
    for (int ch = 0; ch < NCHUNK; ++ch) {                                         \
        const int s = (blockIdx.x * NCHUNK + ch) * 64 + lane;                     \
        float r0 = rel[s * 3], r1 = rel[s * 3 + 1], r2 = rel[s * 3 + 2];          \
        _Pragma("unroll")                                                         \
        for (int i = 0; i < 4; ++i) {                                             \
            const int c0 = wave * 16 + i * 4;                                     \
            float4 av;                                                            \
            { float4 w = W1l[c0];     float2 st = st1[c0];                        \
              av.x = fmaxf(fmaf(st.x, (w.x*r0 + w.y*r1 + w.z*r2) + w.w, st.y), 0.f); } \
            { float4 w = W1l[c0 + 1]; float2 st = st1[c0 + 1];                    \
              av.y = fmaxf(fmaf(st.x, (w.x*r0 + w.y*r1 + w.z*r2) + w.w, st.y), 0.f); } \
            { float4 w = W1l[c0 + 2]; float2 st = st1[c0 + 2];                    \
              av.z = fmaxf(fmaf(st.x, (w.x*r0 + w.y*r1 + w.z*r2) + w.w, st.y), 0.f); } \
            { float4 w = W1l[c0 + 3]; float2 st = st1[c0 + 3];                    \
              av.w = fmaxf(fmaf(st.x, (w.x*r0 + w.y*r1 + w.z*r2) + w.w, st.y), 0.f); } \
            *(float4*)&A[lane][c0] = av;                                          \
            sa4[i].x += av.x; sa4[i].y += av.y; sa4[i].z += av.z; sa4[i].w += av.w; \
        }                                                                         \
        __syncthreads();                                                          \
        _Pragma("unroll 4")                                                       \
        for (int sl = 0; sl < 64; ++sl) {                                         \
            float4 ai = *(const float4*)&A[sl][i0];                               \
            float4 aj = *(const float4*)&A[sl][j0];                               \
            g[0][0] = fmaf(ai.x, aj.x, g[0][0]); g[0][1] = fmaf(ai.x, aj.y, g[0][1]); \
            g[0][2] = fmaf(ai.x, aj.z, g[0][2]); g[0][3] = fmaf(ai.x, aj.w, g[0][3]); \
            g[1][0] = fmaf(ai.y, aj.x, g[1][0]); g[1][1] = fmaf(ai.y, aj.y, g[1][1]); \
            g[1][2] = fmaf(ai.y, aj.z, g[1][2]); g[1][3] = fmaf(ai.y, aj.w, g[1][3]); \
            g[2][0] = fmaf(ai.z, aj.x, g[2][0]); g[2][1] = fmaf(ai.z, aj.y, g[2][1]); \
            g[2][2] = fmaf(ai.z, aj.z, g[2][2]); g[2][3] = fmaf(ai.z, aj.w, g[2][3]); \
            g[3][0] = fmaf(ai.w, aj.x, g[3][0]); g[3][1] = fmaf(ai.w, aj.y, g[3][1]); \
            g[3][2] = fmaf(ai.w, aj.z, g[3][2]); g[3][3] = fmaf(ai.w, aj.w, g[3][3]); \
        }                                                                         \
        __syncthreads();                                                          \
    }                                                                             \
    _Pragma("unroll")                                                             \
    for (int i = 0; i < 4; ++i) {                                                 \
        float4 v = sa4[i];                                                        \
        _Pragma("unroll")                                                         \
        for (int d = 1; d < 64; d <<= 1) {                                        \
            v.x += __shfl_xor(v.x, d, 64); v.y += __shfl_xor(v.y, d, 64);         \
            v.z += __shfl_xor(v.z, d, 64); v.w += __shfl_xor(v.w, d, 64);         \
        }                                                                         \
        sa4[i] = v;                                                               \
    }

// ---------------- K3a (BIG): per-block G partials via bf16 MFMA (R14-verbatim) --------
__global__ __launch_bounds__(256) void gram_part_kernel(const float* __restrict__ rel,
        const float* __restrict__ W1, const float* __restrict__ b1,
        const float* __restrict__ s1t1,
        float* __restrict__ Gpart, float* __restrict__ sapart) {
    __shared__ unsigned short Ab[64 * 64];   // [c][s] bf16, swizzled
    __shared__ float4 W1l[64];
    __shared__ float2 st1[64];
    const int tid = threadIdx.x;
    const int lane = tid & 63, wave = tid >> 6;
    if (tid < 64) {
        W1l[tid] = make_float4(W1[tid * 3], W1[tid * 3 + 1], W1[tid * 3 + 2], b1[tid]);
        st1[tid] = make_float2(s1t1[tid], s1t1[64 + tid]);
    }
    __syncthreads();

    const int sl = lane & 15;
    const int ko = (lane >> 4) * 16;
    f32x4 acc[4];
#pragma unroll
    for (int n = 0; n < 4; ++n) acc[n] = (f32x4){0.f, 0.f, 0.f, 0.f};
    float4 sa4[4];
#pragma unroll
    for (int i = 0; i < 4; ++i) sa4[i] = make_float4(0.f, 0.f, 0.f, 0.f);

#pragma unroll 1
    for (int ch = 0; ch < 8; ++ch) {
        const int s = (blockIdx.x * 8 + ch) * 64 + lane;
        const float r0 = rel[s * 3], r1 = rel[s * 3 + 1], r2 = rel[s * 3 + 2];
#pragma unroll
        for (int i = 0; i < 4; ++i) {
            const int c0 = wave * 16 + i * 4;
            float av[4];
#pragma unroll
            for (int u = 0; u < 4; ++u) {
                float4 w = W1l[c0 + u]; float2 st = st1[c0 + u];
                av[u] = fmaxf(fmaf(st.x, (w.x * r0 + w.y * r1 + w.z * r2) + w.w, st.y), 0.f);
            }
            sa4[i].x += av[0]; sa4[i].y += av[1]; sa4[i].z += av[2]; sa4[i].w += av[3];
#pragma unroll
            for (int u = 0; u < 4; ++u)
                *(unsigned short*)((char*)Ab + swz(c0 + u, lane * 2)) =
                    (unsigned short)bf16r(av[u]);
        }
        __syncthreads();
        short8 aF0 = *(const short8*)((const char*)Ab + swz(wave * 16 + sl, ko));
        short8 aF1 = *(const short8*)((const char*)Ab + swz(wave * 16 + sl, 64 + ko));
#pragma unroll
        for (int n = 0; n < 4; ++n) {
            short8 b0 = *(const short8*)((const char*)Ab + swz(n * 16 + sl, ko));
            short8 b1 = *(const short8*)((const char*)Ab + swz(n * 16 + sl, 64 + ko));
            acc[n] = __builtin_amdgcn_mfma_f32_16x16x32_bf16(aF0, b0, acc[n], 0, 0, 0);
            acc[n] = __builtin_amdgcn_mfma_f32_16x16x32_bf16(aF1, b1, acc[n], 0, 0, 0);
        }
        __syncthreads();
    }
    float* Gp = Gpart + (size_t)blockIdx.x * 4096;
#pragma unroll
    for (int n = 0; n < 4; ++n)
#pragma unroll
        for (int r = 0; r < 4; ++r) {
            const int c1 = wave * 16 + (lane >> 4) * 4 + r;
            const int c2 = n * 16 + sl;
            Gp[c1 * 64 + c2] = acc[n][r];
        }
#pragma unroll
    for (int i = 0; i < 4; ++i) {
        float4 v = sa4[i];
#pragma unroll
        for (int d = 1; d < 64; d <<= 1) {
            v.x += __shfl_xor(v.x, d, 64); v.y += __shfl_xor(v.y, d, 64);
            v.z += __shfl_xor(v.z, d, 64); v.w += __shfl_xor(v.w, d, 64);
        }
        if (lane == 0) {
            float* sp = sapart + (size_t)blockIdx.x * 64 + wave * 16 + i * 4;
            sp[0] = v.x; sp[1] = v.y; sp[2] = v.z; sp[3] = v.w;
        }
    }
}

// ---------------- K3a2 (BIG): parallel 512->1 reduction (R14-verbatim) --------
__global__ __launch_bounds__(256) void gred_kernel(float* __restrict__ Gpart,
                                                   float* __restrict__ sapart) {
    __shared__ double red[4][64];
    const int tid = threadIdx.x;
    const int sub = tid & 63;
    const int j   = tid >> 6;
    const int e   = blockIdx.x * 64 + sub;
    double acc = 0.0;
    if (e < 4096) {
        const float* src = Gpart + e;
        for (int p = j * 128; p < (j + 1) * 128; ++p)
            acc += (double)src[(size_t)p * 4096];
    } else if (e < 4160) {
        const float* src = sapart + (e - 4096);
        for (int p = j * 128; p < (j + 1) * 128; ++p)
            acc += (double)src[(size_t)p * 64];
    }
    red[j][sub] = acc;
    __syncthreads();
    if (j == 0) {
        double t = ((red[0][sub] + red[1][sub]) + red[2][sub]) + red[3][sub];
        if (e < 4096)      Gpart[(size_t)511 * 4096 + e] = (float)t;
        else if (e < 4160) sapart[(size_t)511 * 64 + (e - 4096)] = (float)t;
    }
}

// ---------------- K3b (SMALL fallback, proven R8) ------------
__global__ __launch_bounds__(256) void gram_atomic_kernel(const float* __restrict__ rel,
        const float* __restrict__ W1, const float* __restrict__ b1,
        const float* __restrict__ s1t1, unsigned long long* __restrict__ Gfix) {
    GRAM_BODY(16)
#pragma unroll
    for (int a = 0; a < 4; ++a)
#pragma unroll
        for (int c = 0; c < 4; ++c)
            atomicAdd(&Gfix[(i0 + a) * 64 + (j0 + c)],
                      (unsigned long long)((double)g[a][c] * FIXSCALE));
    if (lane == 0) {
#pragma unroll
        for (int i = 0; i < 4; ++i) {
            const int c0 = wave * 16 + i * 4;
            atomicAdd(&Gfix[4096 + c0 + 0], (unsigned long long)((double)sa4[i].x * FIXSCALE));
            atomicAdd(&Gfix[4096 + c0 + 1], (unsigned long long)((double)sa4[i].y * FIXSCALE));
            atomicAdd(&Gfix[4096 + c0 + 2], (unsigned long long)((double)sa4[i].z * FIXSCALE));
            atomicAdd(&Gfix[4096 + c0 + 3], (unsigned long long)((double)sa4[i].w * FIXSCALE));
        }
    }
}

// ======== shared fin2G tail (R14-verbatim) ========
#define FIN2G_TAIL                                                                \
    const int o = tid & 63, part = tid >> 6;                                      \
    float partial = 0.f;                                                          \
    _Pragma("unroll")                                                             \
    for (int ii = 0; ii < 4; ++ii) {                                              \
        const int i = part * 4 + ii;                                              \
        float t2 = 0.f;                                                           \
        _Pragma("unroll")                                                         \
        for (int j = 0; j < 64; j += 4) {                                         \
            float4 wj = *(const float4*)&w2s[o][j];                               \
            float4 gj = *(const float4*)&Gs[i][j];                                \
            t2 = fmaf(wj.x, gj.x, t2); t2 = fmaf(wj.y, gj.y, t2);                 \
            t2 = fmaf(wj.z, gj.z, t2); t2 = fmaf(wj.w, gj.w, t2);                 \
        }                                                                         \
        partial = fmaf(w2s[o][i], t2, partial);                                   \
    }                                                                             \
    red[part][o] = partial;                                                       \
    __syncthreads();                                                              \
    if (tid < 64) {                                                               \
        double qf = 0.0;                                                          \
        _Pragma("unroll")                                                         \
        for (int p = 0; p < 16; ++p) qf += (double)red[p][tid];                   \
        double SA = 0.0;                                                          \
        for (int c = 0; c < 64; ++c) SA += (double)w2s[tid][c] * (double)sa_s[c]; \
        const double Md = (double)M_SAMPLES;                                      \
        double mean = SA / Md + (double)b2[tid];                                  \
        double var  = qf / Md - (SA / Md) * (SA / Md);                            \
        double sc = (double)gamma[tid] / sqrt(var + 1e-5);                        \
        s2t2[tid]      = (float)sc;                                               \
        s2t2[64 + tid] = (float)((double)beta[tid] - mean * sc);                  \
    }

// ---------------- K4a (BIG): finalize from reduced row 511 (R14-verbatim) -------------
__global__ __launch_bounds__(1024) void fin2G_part_kernel(const float* __restrict__ Gpart,
                            const float* __restrict__ sapart,
                            const float* __restrict__ W2, const float* __restrict__ b2,
                            const float* __restrict__ gamma, const float* __restrict__ beta,
                            float* __restrict__ s2t2) {
    __shared__ float Gs[64][68];
    __shared__ float w2s[64][68];
    __shared__ float sa_s[64];
    __shared__ float red[16][64];
    const int tid = threadIdx.x;
    for (int i = tid; i < 4096; i += 1024) {
        Gs[i >> 6][i & 63]  = Gpart[(size_t)511 * 4096 + i];
        w2s[i >> 6][i & 63] = W2[i];
    }
    if (tid < 64) sa_s[tid] = sapart[(size_t)511 * 64 + tid];
    __syncthreads();
    FIN2G_TAIL
}

// ---------------- K4b (SMALL fallback, proven R8) ----------------
__global__ __launch_bounds__(1024) void fin2G_atomic_kernel(const unsigned long long* __restrict__ Gfix,
                            const float* __restrict__ W2, const float* __restrict__ b2,
                            const float* __restrict__ gamma, const float* __restrict__ beta,
                            float* __restrict__ s2t2) {
    __shared__ float Gs[64][68];
    __shared__ float w2s[64][68];
    __shared__ float sa_s[64];
    __shared__ float red[16][64];
    const int tid = threadIdx.x;
    const double INV = 1.0 / FIXSCALE;
    for (int i = tid; i < 4096; i += 1024) {
        Gs[i >> 6][i & 63]  = (float)((double)Gfix[i] * INV);
        w2s[i >> 6][i & 63] = W2[i];
    }
    if (tid < 64) sa_s[tid] = (float)((double)Gfix[4096 + tid] * INV);
    __syncthreads();
    FIN2G_TAIL
}

// ---------------- K5: MFMA bf16 block-GEMM chain + max over k (R14-verbatim) ----------
__global__ __launch_bounds__(256) void out_kernel(const float* __restrict__ rel,
        const float* __restrict__ W1, const float* __restrict__ b1,
        const float* __restrict__ W2, const float* __restrict__ b2,
        const float* __restrict__ s1t1, const float* __restrict__ s2t2,
        float* __restrict__ out) {
    __shared__ unsigned short Wb[64 * 64];
    __shared__ unsigned short Ab[64 * 64];
    __shared__ float4 W1l[64];
    __shared__ float2 st1[64];
    __shared__ float2 st2[64];
    __shared__ float  b2l[64];

    const int tid = threadIdx.x;
    const int lane = tid & 63, wave = tid >> 6;
    const int sbase = blockIdx.x * 64;

    for (int e = tid; e < 2048; e += 256) {
        const int o = e >> 5, kp = e & 31;
        float2 wv = *(const float2*)&W2[o * 64 + kp * 2];
        unsigned int pk = (bf16r(wv.y) << 16) | bf16r(wv.x);
        *(unsigned int*)((char*)Wb + swz(o, kp * 4)) = pk;
    }
    if (tid < 64) {
        W1l[tid] = make_float4(W1[tid * 3], W1[tid * 3 + 1], W1[tid * 3 + 2], b1[tid]);
        st1[tid] = make_float2(s1t1[tid], s1t1[64 + tid]);
        st2[tid] = make_float2(s2t2[tid], s2t2[64 + tid]);
        b2l[tid] = b2[tid];
    }
    __syncthreads();

    const int sl  = lane & 15;
    const int cg  = lane >> 4;
    const int row = wave * 16 + sl;
    {
        const int sg = sbase + row;
        const float r0 = rel[sg * 3], r1 = rel[sg * 3 + 1], r2 = rel[sg * 3 + 2];
        unsigned int pk[8];
#pragma unroll
        for (int p = 0; p < 8; ++p) {
            const int c = cg * 16 + p * 2;
            float4 wA = W1l[c];     float2 sA = st1[c];
            float4 wB = W1l[c + 1]; float2 sB = st1[c + 1];
            float a0 = fmaxf(fmaf(sA.x, (wA.x * r0 + wA.y * r1 + wA.z * r2) + wA.w, sA.y), 0.f);
            float a1 = fmaxf(fmaf(sB.x, (wB.x * r0 + wB.y * r1 + wB.z * r2) + wB.w, sB.y), 0.f);
            pk[p] = (bf16r(a1) << 16) | bf16r(a0);
        }
        *(uint4*)((char*)Ab + swz(row, cg * 32))      = make_uint4(pk[0], pk[1], pk[2], pk[3]);
        *(uint4*)((char*)Ab + swz(row, cg * 32 + 16)) = make_uint4(pk[4], pk[5], pk[6], pk[7]);
    }

    const int ko = (lane >> 4) * 16;

    short8 bF0 = *(const short8*)((const char*)Ab + swz(wave * 16 + sl, ko));
    short8 bF1 = *(const short8*)((const char*)Ab + swz(wave * 16 + sl, 64 + ko));
    f32x4 acc1[4];
#pragma unroll
    for (int m = 0; m < 4; ++m) {
        f32x4 acc = {0.f, 0.f, 0.f, 0.f};
        short8 aF0 = *(const short8*)((const char*)Wb + swz(m * 16 + sl, ko));
        acc = __builtin_amdgcn_mfma_f32_16x16x32_bf16(aF0, bF0, acc, 0, 0, 0);
        short8 aF1 = *(const short8*)((const char*)Wb + swz(m * 16 + sl, 64 + ko));
        acc = __builtin_amdgcn_mfma_f32_16x16x32_bf16(aF1, bF1, acc, 0, 0, 0);
        acc1[m] = acc;
    }
#pragma unroll
    for (int m = 0; m < 4; ++m) {
        const int ob = m * 16 + (lane >> 4) * 4;
        unsigned int q0, q1;
        {
            float2 s0 = st2[ob + 0], s1 = st2[ob + 1];
            float v0 = fmaxf(fmaf(s0.x, acc1[m][0] + b2l[ob + 0], s0.y), 0.f);
            float v1 = fmaxf(fmaf(s1.x, acc1[m][1] + b2l[ob + 1], s1.y), 0.f);
            q0 = (bf16r(v1) << 16) | bf16r(v0);
        }
        {
            float2 s2v = st2[ob + 2], s3 = st2[ob + 3];
            float v2 = fmaxf(fmaf(s2v.x, acc1[m][2] + b2l[ob + 2], s2v.y), 0.f);
            float v3 = fmaxf(fmaf(s3.x, acc1[m][3] + b2l[ob + 3], s3.y), 0.f);
            q1 = (bf16r(v3) << 16) | bf16r(v2);
        }
        *(uint2*)((char*)Ab + swz(wave * 16 + sl, ob * 2)) = make_uint2(q0, q1);
    }

    short8 cF0 = *(const short8*)((const char*)Ab + swz(wave * 16 + sl, ko));
    short8 cF1 = *(const short8*)((const char*)Ab + swz(wave * 16 + sl, 64 + ko));
    const int qg = sbase / 16 + wave;
    const int bb = qg >> 11;
    const int nn = qg & (NPTS - 1);
#pragma unroll
    for (int m = 0; m < 4; ++m) {
        f32x4 acc = {0.f, 0.f, 0.f, 0.f};
        short8 aF0 = *(const short8*)((const char*)Wb + swz(m * 16 + sl, ko));
        acc = __builtin_amdgcn_mfma_f32_16x16x32_bf16(aF0, cF0, acc, 0, 0, 0);
        short8 aF1 = *(const short8*)((const char*)Wb + swz(m * 16 + sl, 64 + ko));
        acc = __builtin_amdgcn_mfma_f32_16x16x32_bf16(aF1, cF1, acc, 0, 0, 0);
        const int ob = m * 16 + (lane >> 4) * 4;
#pragma unroll
        for (int r = 0; r < 4; ++r) {
            float v = acc[r] + b2l[ob + r];
            v = fmaxf(v, __shfl_xor(v, 1, 64));
            v = fmaxf(v, __shfl_xor(v, 2, 64));
            v = fmaxf(v, __shfl_xor(v, 4, 64));
            v = fmaxf(v, __shfl_xor(v, 8, 64));
            if ((lane & 15) == 0)
                out[(size_t)bb * (CH * NPTS) + (ob + r) * NPTS + nn] = v;
        }
    }
}

extern "C" void kernel_launch(void* const* d_in, const int* in_sizes, int n_in,
                              void* d_out, int out_size, void* d_ws, size_t ws_size,
                              hipStream_t stream) {
    (void)in_sizes; (void)n_in; (void)out_size;
    const float* xyz   = (const float*)d_in[0];
    const float* W1    = (const float*)d_in[1];
    const float* b1    = (const float*)d_in[2];
    const float* W2    = (const float*)d_in[3];
    const float* b2    = (const float*)d_in[4];
    const float* gamma = (const float*)d_in[5];
    const float* beta  = (const float*)d_in[6];
    float* out = (float*)d_out;
    float* ws  = (float*)d_ws;

    float* rel    = ws + WS_REL;
    float* s1t1   = ws + WS_S1T1;
    float* s2t2   = ws + WS_S2T2;
    float* part1  = ws + WS_PART1;
    float* Gpart  = ws + WS_GPART;
    float* sapart = ws + WS_SAPART;
    unsigned long long* Gfix = (unsigned long long*)(ws + WS_GFIX);

    const bool big = ws_size >= WS_BIG_FLOATS * 4ull;   // constant -> capture-safe

    knn_rel_kernel<<<dim3(4096), dim3(256), 0, stream>>>(xyz, rel, part1);
    fin1_kernel<<<dim3(1), dim3(256), 0, stream>>>(part1, W1, b1, gamma, beta, s1t1, Gfix);
    if (big) {
        gram_part_kernel<<<dim3(GPART_BLKS), dim3(256), 0, stream>>>(rel, W1, b1, s1t1, Gpart, sapart);
        gred_kernel<<<dim3(65), dim3(256), 0, stream>>>(Gpart, sapart);
        fin2G_part_kernel<<<dim3(1), dim3(1024), 0, stream>>>(Gpart, sapart, W2, b2, gamma, beta, s2t2);
    } else {
        gram_atomic_kernel<<<dim3(256), dim3(256), 0, stream>>>(rel, W1, b1, s1t1, Gfix);
        fin2G_atomic_kernel<<<dim3(1), dim3(1024), 0, stream>>>(Gfix, W2, b2, gamma, beta, s2t2);
    }
    out_kernel<<<dim3(4096), dim3(256), 0, stream>>>(rel, W1, b1, W2, b2, s1t1, s2t2, out);
}